// Round 4
// baseline (328.365 us; speedup 1.0000x reference)
//
#include <hip/hip_runtime.h>
#include <hip/hip_bf16.h>
#include <float.h>

// Problem constants
#define NPIX   32768      // B*H*W
#define CDIM   128
#define KCB    8192
#define EPS_STOP 0.30f    // mask quant (0.031) + f16-dot error bound
#define TAUF   0.012f     // exact fp32 gap guard -> fp64 arbitration
#define RCAP   8192
#define RCAPA  2048

typedef _Float16 f16x8 __attribute__((ext_vector_type(8)));
typedef float    f32x16 __attribute__((ext_vector_type(16)));

// ws layout (bytes)
#define WS_EMBFH   0           // 2,359,296
#define WS_E2      2359296     // 32,768
#define WS_ZWS     2392064     // 16,777,216
#define WS_CAND    19169280    // 1,048,576
#define WS_IDX     20217856    // 131,072
#define WS_RLISTA  20348928    // 32,768 (cap 2048 used)
#define WS_RLISTB  20381696    // 131,072 (8192 * int4)
#define WS_SCAND   20512768    // 524,288 (2048*32 double)
#define WS_SCANI   21037056    // 262,144 (2048*32 int)
#define WS_COUNTS  21299200    // 32,768
#define WS_LOSS    21331968    // 4
#define WS_RCNTA   21331972    // 4
#define WS_RCNTB   21331976    // 4
#define WS_ZERO_OFF 21299200
#define WS_ZERO_LEN 32780

// d_out layout (f32): [0]=loss, [1..4194304]=out BCHW, [4194305]=perplexity, [4194306..]=idx
#define OUT_OFF_OUT  1
#define OUT_OFF_PERP 4194305
#define OUT_OFF_IDX  4194306

__device__ __forceinline__ float min3f(float a, float b, float c) {
    return fminf(fminf(a, b), c);   // -> v_min3_f32
}

__device__ __forceinline__ void ins6(float f, float v[6]) {
    float a = fmaxf(v[0], f); v[0] = fminf(v[0], f);
    float b = fmaxf(v[1], a); v[1] = fminf(v[1], a);
    a = fmaxf(v[2], b); v[2] = fminf(v[2], b);
    b = fmaxf(v[3], a); v[3] = fminf(v[3], a);
    a = fmaxf(v[4], b); v[4] = fminf(v[4], b);
    v[5] = fminf(v[5], a);
}

__device__ __forceinline__ float packmin(float m, uint32_t id) {
    return __uint_as_float((__float_as_uint(m) & 0xFFFFFE00u) | id);
}

// ---------------- K0: e2[k] = sum_c emb[k][c]^2 ----------------
__global__ __launch_bounds__(256) void k_e2(const float* __restrict__ emb, float* __restrict__ e2) {
    int t = threadIdx.x;
    int wv = t >> 6, l = t & 63;
    int k = blockIdx.x * 4 + wv;
    const float2 v = *(const float2*)&emb[(size_t)k * 128 + l * 2];
    float s = v.x * v.x + v.y * v.y;
    #pragma unroll
    for (int o = 32; o; o >>= 1) s += __shfl_down(s, o, 64);
    if (l == 0) e2[k] = s;
}

// ---------------- K1: fragment-ordered -2*emb (f16), e2+512 hi/lo fold in step 8 ----------------
__global__ __launch_bounds__(256) void k_prep(const float* __restrict__ emb, const float* __restrict__ e2,
                                              _Float16* __restrict__ embFh) {
    int tid = blockIdx.x * 256 + threadIdx.x;   // < 147456 = 8192*18
    int m = tid / 18, r = tid % 18;
    int s = r >> 1, h = r & 1;
    f16x8 hv;
    #pragma unroll
    for (int j = 0; j < 8; ++j) hv[j] = (_Float16)0.0f;
    if (s < 8) {
        int c0 = s * 16 + h * 8;
        const float4 a = *(const float4*)&emb[(size_t)m * 128 + c0];
        const float4 b = *(const float4*)&emb[(size_t)m * 128 + c0 + 4];
        float vals[8] = {a.x, a.y, a.z, a.w, b.x, b.y, b.z, b.w};
        #pragma unroll
        for (int j = 0; j < 8; ++j) hv[j] = (_Float16)(-2.0f * vals[j]);
    } else if (h == 0) {
        float v = e2[m] + 512.0f;    // offset keeps packed values > 0 (z2 dropped)
        _Float16 eh = (_Float16)v;
        hv[0] = eh;                  // x B8[0]=1
        hv[1] = (_Float16)(v - (float)eh);   // x B8[1]=1
    }
    size_t base = (((size_t)(m >> 5) * 9 + s) * 64 + (m & 31) + h * 32) * 8;
    *(f16x8*)&embFh[base] = hv;
}

// ---------------- K2: fused linear + MFMA + packed group-min top-6 ----------------
// 512 thr / 8 waves, ONE output tile per wave (B-tile = w>>2, codebook tiles g == w&3 mod 4).
// Per tile-eval: 9 MFMAs split over 4 parity chains c[s&3] -> same-chain interleave
// distance 4 (128 pipe cycles) to cover dependent-MFMA latency. Two chain-sets P/Q
// ping-pong so each tile's tail (parity sum + tree16 + ins6) is deferred one full
// burst. Single A buffer; refill placed right after each burst's issue.
__global__ __launch_bounds__(512, 2) void k_main(
    const float* __restrict__ x, const float* __restrict__ Wl, const float* __restrict__ bl,
    const _Float16* __restrict__ embFh,
    float* __restrict__ zws, float4* __restrict__ cand)
{
    __shared__ __align__(16) float As[64 * 132];   // z [p][c], pitch 132
    __shared__ __align__(16) float Xs[64 * 66];    // x staging / merge scratch
    __shared__ float z2p[64 * 8];                  // z^2 partials [p][ig]

    const int t  = threadIdx.x;
    const int n0 = blockIdx.x * 64;
    const int b  = n0 >> 10;
    const int hw0 = n0 & 1023;

    // ===== Phase 1: z for 64 pixels (8 ig-groups x 16 channels) =====
    {
        const int p = t & 63, ig = t >> 6;
        float accz[16];
        const float4* bl4 = (const float4*)(bl + ig * 16);
        #pragma unroll
        for (int q = 0; q < 4; ++q) {
            float4 v = bl4[q];
            accz[4*q+0] = v.x; accz[4*q+1] = v.y; accz[4*q+2] = v.z; accz[4*q+3] = v.w;
        }
        for (int hf = 0; hf < 2; ++hf) {
            __syncthreads();
            for (int r = 0; r < 8; ++r) {
                int lin = r * 512 + t;
                int cc = lin >> 6, pp = lin & 63;
                Xs[cc * 66 + pp] = x[(size_t)(b * 128 + hf * 64 + cc) * 1024 + hw0 + pp];
            }
            __syncthreads();
            for (int cc4 = 0; cc4 < 16; ++cc4) {
                float xv0 = Xs[(cc4*4+0) * 66 + p];
                float xv1 = Xs[(cc4*4+1) * 66 + p];
                float xv2 = Xs[(cc4*4+2) * 66 + p];
                float xv3 = Xs[(cc4*4+3) * 66 + p];
                #pragma unroll
                for (int ii = 0; ii < 16; ++ii) {
                    const float4 w4 = *(const float4*)&Wl[(size_t)(ig*16+ii) * 128 + hf*64 + cc4*4];
                    float a = accz[ii];
                    a = fmaf(w4.x, xv0, a);
                    a = fmaf(w4.y, xv1, a);
                    a = fmaf(w4.z, xv2, a);
                    a = fmaf(w4.w, xv3, a);
                    accz[ii] = a;
                }
            }
        }
        float ssq = 0.f;
        float4* ao = (float4*)&As[p * 132 + ig * 16];
        float4* zo = (float4*)(zws + (size_t)(n0 + p) * 128 + ig * 16);
        #pragma unroll
        for (int q = 0; q < 4; ++q) {
            float4 v = make_float4(accz[4*q+0], accz[4*q+1], accz[4*q+2], accz[4*q+3]);
            ao[q] = v;
            zo[q] = v;
            ssq = fmaf(v.x, v.x, fmaf(v.y, v.y, fmaf(v.z, v.z, fmaf(v.w, v.w, ssq))));
        }
        z2p[p * 8 + ig] = ssq;
    }
    __syncthreads();

    // ===== Phase 2: B fragments (z f16) for this wave's B-tile + constant fold step =====
    const int l = t & 63, w = t >> 6;
    const int half = l >> 5, pcol = l & 31;
    const int px = ((w >> 2) << 5) + pcol;       // pixel within block (0..63)
    f16x8 B[9];
    #pragma unroll
    for (int s = 0; s < 8; ++s) {
        const float* zp = &As[px * 132 + s * 16 + half * 8];
        float4 v0 = *(const float4*)zp;
        float4 v1 = *(const float4*)(zp + 4);
        float vals[8] = {v0.x, v0.y, v0.z, v0.w, v1.x, v1.y, v1.z, v1.w};
        f16x8 hh;
        #pragma unroll
        for (int j2 = 0; j2 < 8; ++j2) hh[j2] = (_Float16)vals[j2];
        B[s] = hh;
    }
    {
        f16x8 b8;
        #pragma unroll
        for (int j2 = 0; j2 < 8; ++j2) b8[j2] = (_Float16)0.0f;
        if (half == 0) { b8[0] = (_Float16)1.0f; b8[1] = (_Float16)1.0f; }
        B[8] = b8;
    }

    // ===== Phase 3: K-loop, 4-chain distance-4 bursts, P/Q deferred tails =====
    auto tree16 = [](const f32x16& v) -> float {
        float a = min3f(v[0], v[1], v[2]);
        float bb = min3f(v[3], v[4], v[5]);
        float c = min3f(v[6], v[7], v[8]);
        float d = min3f(v[9], v[10], v[11]);
        float e = min3f(v[12], v[13], v[14]);
        float f = min3f(a, bb, c);
        float g = min3f(d, e, v[15]);
        return fminf(f, g);
    };

    float gv[6] = {3e38f, 3e38f, 3e38f, 3e38f, 3e38f, 3e38f};
    const f16x8* Ahp = (const f16x8*)embFh;
    const int gbase = w & 3;
    f16x8 aC[9];
    f32x16 P[4], Q[4];

    #define LOADA(i_) { \
        const f16x8* Pp = Ahp + (size_t)(gbase + 4 * (i_)) * 576 + l; \
        _Pragma("unroll") \
        for (int s = 0; s < 9; ++s) aC[s] = Pp[s * 64]; \
    }
    #define BURST(C_) { \
        _Pragma("unroll") \
        for (int c = 0; c < 4; ++c) C_[c] = (f32x16){}; \
        _Pragma("unroll") \
        for (int s = 0; s < 9; ++s) \
            C_[s & 3] = __builtin_amdgcn_mfma_f32_32x32x16_f16(aC[s], B[s], C_[s & 3], 0, 0, 0); \
    }
    #define TAIL(C_, i_) { \
        f32x16 s0; \
        _Pragma("unroll") \
        for (int r = 0; r < 16; ++r) s0[r] = (C_[0][r] + C_[1][r]) + (C_[2][r] + C_[3][r]); \
        float m0 = tree16(s0); \
        uint32_t id = (uint32_t)(((gbase + 4 * (i_)) << 1) | half); \
        ins6(packmin(m0, id), gv); \
    }

    LOADA(0);
    BURST(P);           // tile 0
    LOADA(1);
    for (int i = 0; i < 31; ++i) {
        BURST(Q);       // tile 2i+1
        LOADA(2 * i + 2);
        TAIL(P, 2 * i);
        BURST(P);       // tile 2i+2
        LOADA(2 * i + 3);
        TAIL(Q, 2 * i + 1);
    }
    BURST(Q);           // tile 63
    TAIL(P, 62);
    TAIL(Q, 63);

    #undef LOADA
    #undef BURST
    #undef TAIL

    // ===== Phase 4: cross-wave merge per pixel, write cand (6 groups + z2) =====
    __syncthreads();
    float* Ms = Xs;   // [64 px][8 slots][6]
    const int slot = ((w & 3) << 1) | half;
    #pragma unroll
    for (int q = 0; q < 6; ++q) Ms[(px * 8 + slot) * 6 + q] = gv[q];
    __syncthreads();
    if (t < 64) {
        float v6[6] = {3e38f, 3e38f, 3e38f, 3e38f, 3e38f, 3e38f};
        #pragma unroll
        for (int s = 0; s < 48; ++s) ins6(Ms[t * 48 + s], v6);
        float z2 = 0.f;
        #pragma unroll
        for (int q = 0; q < 8; ++q) z2 += z2p[t * 8 + q];
        cand[(size_t)(n0 + t) * 2 + 0] = make_float4(v6[0], v6[1], v6[2], v6[3]);
        cand[(size_t)(n0 + t) * 2 + 1] = make_float4(v6[4], v6[5], z2, 0.f);
    }
}

// ---------------- K3: early-exit exact fp32 over candidate groups ----------------
// Packed id decode: id = bits[8:0], tile = id>>1, half = id&1;
// group codes m = tile*32 + half*4 + {(c&3) + 8*(c>>2)}.
// Flags: !safe -> rlistA (parallel full scan); near-tie -> rlistB (fp64 pair arb).
__global__ __launch_bounds__(256) void k_rec(
    const float* __restrict__ zws, const float* __restrict__ emb,
    const float4* __restrict__ cand, int* __restrict__ idxws,
    float* __restrict__ out_idxf, float* __restrict__ losssum,
    int* __restrict__ rlistA, int* __restrict__ rcntA,
    int* __restrict__ rlistB, int* __restrict__ rcntB)
{
    __shared__ float lred[16];
    const int t = threadIdx.x;
    const int pl = t >> 4, j = t & 15;
    const int n = blockIdx.x * 16 + pl;

    const float4 za = *(const float4*)&zws[(size_t)n * 128 + j * 8];
    const float4 zb = *(const float4*)&zws[(size_t)n * 128 + j * 8 + 4];
    const float4 c0 = cand[(size_t)n * 2 + 0];
    const float4 c1 = cand[(size_t)n * 2 + 1];
    const float pv[6] = {c0.x, c0.y, c0.z, c0.w, c1.x, c1.y};
    const float pbase = c1.z - 512.0f;   // d = packed + pbase

    float d1 = 3e38f, d2 = 3e38f; int i1 = 0x7fffffff, i2 = 0x7fffffff;
    bool safe = false;
    float lastgmin = 0.f;
    for (int q = 0; q < 6; ++q) {
        uint32_t bits = __float_as_uint(pv[q]);
        float gmin = __uint_as_float(bits & 0xFFFFFE00u);
        lastgmin = gmin;
        if (gmin >= d1 - pbase + EPS_STOP) { safe = true; break; }
        const int mbase = (int)((bits >> 1) & 255u) * 32 + (int)((bits & 1u) << 2); // tile*32 + half*4
        #pragma unroll
        for (int c = 0; c < 16; ++c) {
            int m = mbase + (c & 3) + 8 * (c >> 2);
            const float4 ea = *(const float4*)&emb[(size_t)m * 128 + j * 8];
            const float4 eb = *(const float4*)&emb[(size_t)m * 128 + j * 8 + 4];
            float da0 = za.x - ea.x, da1 = za.y - ea.y, da2 = za.z - ea.z, da3 = za.w - ea.w;
            float db0 = zb.x - eb.x, db1 = zb.y - eb.y, db2 = zb.z - eb.z, db3 = zb.w - eb.w;
            float s = da0*da0; s = fmaf(da1, da1, s); s = fmaf(da2, da2, s); s = fmaf(da3, da3, s);
            s = fmaf(db0, db0, s); s = fmaf(db1, db1, s); s = fmaf(db2, db2, s); s = fmaf(db3, db3, s);
            s += __shfl_xor(s, 1, 16);
            s += __shfl_xor(s, 2, 16);
            s += __shfl_xor(s, 4, 16);
            s += __shfl_xor(s, 8, 16);
            if (s < d1 || (s == d1 && m < i1)) { d2 = d1; i2 = i1; d1 = s; i1 = m; }
            else if (s < d2) { d2 = s; i2 = m; }
        }
    }
    if (!safe && lastgmin >= d1 - pbase + EPS_STOP) safe = true;  // post-check vs pv[5]

    if (j == 0) {
        idxws[n] = i1;
        out_idxf[n] = (float)i1;
        if (!safe) {
            int s = atomicAdd(rcntA, 1);
            if (s < RCAPA) rlistA[s] = n;
        } else if ((d2 - d1) < TAUF) {
            int s = atomicAdd(rcntB, 1);
            if (s < RCAP) { int4 v4 = make_int4(n, i1, i2, 0); ((int4*)rlistB)[s] = v4; }
        }
        lred[pl] = d1;
    }
    __syncthreads();
    if (t == 0) {
        float ls = 0.f;
        #pragma unroll
        for (int q = 0; q < 16; ++q) ls += lred[q];
        atomicAdd(losssum, ls);
    }
}

// ---------------- K4a: parallel full scan for !safe pixels ----------------
// 32 chunk-blocks per pixel, 256 codes/chunk; 16 lanes/code coalesced; fp64 accum.
__global__ __launch_bounds__(256) void k_scanp(
    const float* __restrict__ zws, const float* __restrict__ emb,
    const int* __restrict__ rcntA, const int* __restrict__ rlistA,
    double* __restrict__ scand, int* __restrict__ scani)
{
    int cnt = *rcntA; if (cnt > RCAPA) cnt = RCAPA;
    const int t = threadIdx.x;
    const int chunk = blockIdx.x & 31;
    const int gi = t >> 4, j = t & 15;
    __shared__ double sd[16];
    __shared__ int si[16];
    for (int e = blockIdx.x >> 5; e < cnt; e += 64) {
        const int n = rlistA[e];
        const float4 za = *(const float4*)&zws[(size_t)n * 128 + j * 8];
        const float4 zb = *(const float4*)&zws[(size_t)n * 128 + j * 8 + 4];
        double best = 1e300; int bi = 0x7fffffff;
        const int kbase = chunk * 256 + gi * 16;
        for (int c = 0; c < 16; ++c) {
            const int m = kbase + c;
            const float4 ea = *(const float4*)&emb[(size_t)m * 128 + j * 8];
            const float4 eb = *(const float4*)&emb[(size_t)m * 128 + j * 8 + 4];
            double s = 0.0, d;
            d = (double)za.x - (double)ea.x; s += d * d;
            d = (double)za.y - (double)ea.y; s += d * d;
            d = (double)za.z - (double)ea.z; s += d * d;
            d = (double)za.w - (double)ea.w; s += d * d;
            d = (double)zb.x - (double)eb.x; s += d * d;
            d = (double)zb.y - (double)eb.y; s += d * d;
            d = (double)zb.z - (double)eb.z; s += d * d;
            d = (double)zb.w - (double)eb.w; s += d * d;
            s += __shfl_xor(s, 1, 16);
            s += __shfl_xor(s, 2, 16);
            s += __shfl_xor(s, 4, 16);
            s += __shfl_xor(s, 8, 16);
            if (s < best) { best = s; bi = m; }   // m strictly increasing -> first-index
        }
        __syncthreads();
        if (j == 0) { sd[gi] = best; si[gi] = bi; }
        __syncthreads();
        if (t == 0) {
            double b = sd[0]; int ib = si[0];
            #pragma unroll
            for (int q = 1; q < 16; ++q)
                if (sd[q] < b || (sd[q] == b && si[q] < ib)) { b = sd[q]; ib = si[q]; }
            scand[e * 32 + chunk] = b;
            scani[e * 32 + chunk] = ib;
        }
    }
}

// ---------------- K4b: merge 32 chunk results per !safe pixel ----------------
__global__ __launch_bounds__(64) void k_mergeA(
    const int* __restrict__ rcntA, const int* __restrict__ rlistA,
    const double* __restrict__ scand, const int* __restrict__ scani,
    int* __restrict__ idxws, float* __restrict__ out_idxf)
{
    int cnt = *rcntA; if (cnt > RCAPA) cnt = RCAPA;
    const int t = threadIdx.x;
    for (int e = blockIdx.x; e < cnt; e += gridDim.x) {
        double b = 1e300; int ib = 0x7fffffff;
        if (t < 32) { b = scand[e * 32 + t]; ib = scani[e * 32 + t]; }
        #pragma unroll
        for (int o = 16; o; o >>= 1) {
            double ob = __shfl_down(b, o, 64);
            int oi = __shfl_down(ib, o, 64);
            if (ob < b || (ob == b && oi < ib)) { b = ob; ib = oi; }
        }
        if (t == 0) { int n = rlistA[e]; idxws[n] = ib; out_idxf[n] = (float)ib; }
    }
}

// ---------------- K4c: fp64 pair arbitration for near-tie pixels ----------------
__global__ __launch_bounds__(128) void k_pairB(
    const float* __restrict__ x, const float* __restrict__ Wl, const float* __restrict__ bl,
    const float* __restrict__ emb, const int* __restrict__ rcntB, const int* __restrict__ rlistB,
    int* __restrict__ idxws, float* __restrict__ out_idxf)
{
    __shared__ double xs[128];
    __shared__ double red[128];
    int cnt = *rcntB; if (cnt > RCAP) cnt = RCAP;
    const int t = threadIdx.x;
    for (int e = blockIdx.x; e < cnt; e += gridDim.x) {
        const int4 v = ((const int4*)rlistB)[e];
        const int n = v.x, c1 = v.y, c2 = v.z;
        const int b = n >> 10, hw = n & 1023;
        __syncthreads();
        xs[t] = (double)x[(size_t)(b * 128 + t) * 1024 + hw];
        __syncthreads();
        double z = (double)bl[t];
        for (int c = 0; c < 128; ++c) z = fma((double)Wl[(size_t)t * 128 + c], xs[c], z);
        double d1v, d2v;
        double da = z - (double)emb[(size_t)c1 * 128 + t];
        red[t] = da * da; __syncthreads();
        for (int o = 64; o; o >>= 1) { if (t < o) red[t] += red[t + o]; __syncthreads(); }
        d1v = red[0]; __syncthreads();
        double db = z - (double)emb[(size_t)c2 * 128 + t];
        red[t] = db * db; __syncthreads();
        for (int o = 64; o; o >>= 1) { if (t < o) red[t] += red[t + o]; __syncthreads(); }
        d2v = red[0];
        if (t == 0) {
            int win = (d2v < d1v || (d2v == d1v && c2 < c1)) ? c2 : c1;
            idxws[n] = win;
            out_idxf[n] = (float)win;
        }
        __syncthreads();
    }
}

// ---------------- K5: gather + transpose + histogram ----------------
__global__ __launch_bounds__(256) void k_out(
    const float* __restrict__ emb, const int* __restrict__ idxws,
    float* __restrict__ outp /* d_out + 1 */, float* __restrict__ counts)
{
    const int t = threadIdx.x;
    const int b = blockIdx.x >> 2, h0 = (blockIdx.x & 3) << 3;
    const int n = b * 1024 + h0 * 32 + t;
    const int id = idxws[n];
    atomicAdd(&counts[id], 1.0f);
    const float4* ep = (const float4*)&emb[(size_t)id * 128];
    float* ob = outp + (size_t)b * 131072 + h0 * 32 + t;
    #pragma unroll 4
    for (int c4 = 0; c4 < 32; ++c4) {
        float4 v = ep[c4];
        ob[(c4 * 4 + 0) * 1024] = v.x;
        ob[(c4 * 4 + 1) * 1024] = v.y;
        ob[(c4 * 4 + 2) * 1024] = v.z;
        ob[(c4 * 4 + 3) * 1024] = v.w;
    }
}

// ---------------- K6: finalize loss + perplexity ----------------
__global__ __launch_bounds__(256) void k_final(
    const float* __restrict__ counts, const float* __restrict__ losssum, float* __restrict__ d_out)
{
    const int t = threadIdx.x;
    float ent = 0.f;
    for (int k = t; k < KCB; k += 256) {
        float p = counts[k] * (1.0f / 32768.0f);
        ent -= p * logf(p + 1e-10f);
    }
    #pragma unroll
    for (int o = 32; o; o >>= 1) ent += __shfl_down(ent, o, 64);
    __shared__ float wred[4];
    if ((t & 63) == 0) wred[t >> 6] = ent;
    __syncthreads();
    if (t == 0) {
        float e = wred[0] + wred[1] + wred[2] + wred[3];
        d_out[0] = 1.25f * (*losssum) * (1.0f / 4194304.0f);
        d_out[OUT_OFF_PERP] = expf(e);
    }
}

extern "C" void kernel_launch(void* const* d_in, const int* in_sizes, int n_in,
                              void* d_out, int out_size, void* d_ws, size_t ws_size,
                              hipStream_t stream) {
    (void)in_sizes; (void)n_in; (void)out_size; (void)ws_size;
    const float* x   = (const float*)d_in[0];
    const float* Wl  = (const float*)d_in[1];
    const float* bl  = (const float*)d_in[2];
    const float* emb = (const float*)d_in[3];
    float* out = (float*)d_out;
    char*  ws  = (char*)d_ws;

    _Float16* embFh = (_Float16*)(ws + WS_EMBFH);
    float* e2      = (float*)(ws + WS_E2);
    float* zws     = (float*)(ws + WS_ZWS);
    float4* cand   = (float4*)(ws + WS_CAND);
    int*   idxws   = (int*)  (ws + WS_IDX);
    int*   rlistA  = (int*)  (ws + WS_RLISTA);
    int*   rlistB  = (int*)  (ws + WS_RLISTB);
    double* scand  = (double*)(ws + WS_SCAND);
    int*   scani   = (int*)  (ws + WS_SCANI);
    float* counts  = (float*)(ws + WS_COUNTS);
    float* losssum = (float*)(ws + WS_LOSS);
    int*   rcntA   = (int*)  (ws + WS_RCNTA);
    int*   rcntB   = (int*)  (ws + WS_RCNTB);

    hipMemsetAsync(ws + WS_ZERO_OFF, 0, WS_ZERO_LEN, stream);

    k_e2<<<KCB / 4, 256, 0, stream>>>(emb, e2);
    k_prep<<<576, 256, 0, stream>>>(emb, e2, embFh);
    k_main<<<NPIX / 64, 512, 0, stream>>>(x, Wl, bl, embFh, zws, cand);
    k_rec<<<NPIX / 16, 256, 0, stream>>>(zws, emb, cand, idxws, out + OUT_OFF_IDX,
                                         losssum, rlistA, rcntA, rlistB, rcntB);
    k_scanp<<<2048, 256, 0, stream>>>(zws, emb, rcntA, rlistA, scand, scani);
    k_mergeA<<<32, 64, 0, stream>>>(rcntA, rlistA, scand, scani, idxws, out + OUT_OFF_IDX);
    k_pairB<<<256, 128, 0, stream>>>(x, Wl, bl, emb, rcntB, rlistB, idxws, out + OUT_OFF_IDX);
    k_out<<<128, 256, 0, stream>>>(emb, idxws, out + OUT_OFF_OUT, counts);
    k_final<<<1, 256, 0, stream>>>(counts, losssum, out);
}

// Round 5
// 304.955 us; speedup vs baseline: 1.0768x; 1.0768x over previous
//
#include <hip/hip_runtime.h>
#include <hip/hip_bf16.h>
#include <float.h>

// Problem constants
#define NPIX   32768      // B*H*W
#define CDIM   128
#define KCB    8192
#define EPS_STOP 0.30f    // mask quant (0.031) + f16-dot error bound
#define TAUF   0.012f     // exact fp32 gap guard -> fp64 arbitration
#define RCAP   8192
#define RCAPA  2048

typedef _Float16 f16x8 __attribute__((ext_vector_type(8)));
typedef float    f32x16 __attribute__((ext_vector_type(16)));

// ws layout (bytes)
#define WS_EMBFH   0           // 2,359,296
#define WS_E2      2359296     // 32,768
#define WS_ZWS     2392064     // 16,777,216
#define WS_CAND    19169280    // 1,048,576
#define WS_IDX     20217856    // 131,072
#define WS_RLISTA  20348928    // 32,768 (cap 2048 used)
#define WS_RLISTB  20381696    // 131,072 (8192 * int4)
#define WS_SCAND   20512768    // 524,288 (2048*32 double)
#define WS_SCANI   21037056    // 262,144 (2048*32 int)
#define WS_COUNTS  21299200    // 32,768
#define WS_LOSS    21331968    // 4
#define WS_RCNTA   21331972    // 4
#define WS_RCNTB   21331976    // 4
#define WS_ZERO_OFF 21299200
#define WS_ZERO_LEN 32780

// d_out layout (f32): [0]=loss, [1..4194304]=out BCHW, [4194305]=perplexity, [4194306..]=idx
#define OUT_OFF_OUT  1
#define OUT_OFF_PERP 4194305
#define OUT_OFF_IDX  4194306

__device__ __forceinline__ float min3f(float a, float b, float c) {
    return fminf(fminf(a, b), c);   // -> v_min3_f32
}

__device__ __forceinline__ void ins6(float f, float v[6]) {
    float a = fmaxf(v[0], f); v[0] = fminf(v[0], f);
    float b = fmaxf(v[1], a); v[1] = fminf(v[1], a);
    a = fmaxf(v[2], b); v[2] = fminf(v[2], b);
    b = fmaxf(v[3], a); v[3] = fminf(v[3], a);
    a = fmaxf(v[4], b); v[4] = fminf(v[4], b);
    v[5] = fminf(v[5], a);
}

__device__ __forceinline__ float packmin(float m, uint32_t id) {
    return __uint_as_float((__float_as_uint(m) & 0xFFFFFE00u) | id);
}

// async global -> LDS, 16 B per lane (literal size per guide)
__device__ __forceinline__ void gload16(const void* gp, void* lp) {
    __builtin_amdgcn_global_load_lds(
        (const __attribute__((address_space(1))) void*)gp,
        (__attribute__((address_space(3))) void*)lp,
        16, 0, 0);
}

// ---------------- K0: e2[k] = sum_c emb[k][c]^2 ----------------
__global__ __launch_bounds__(256) void k_e2(const float* __restrict__ emb, float* __restrict__ e2) {
    int t = threadIdx.x;
    int wv = t >> 6, l = t & 63;
    int k = blockIdx.x * 4 + wv;
    const float2 v = *(const float2*)&emb[(size_t)k * 128 + l * 2];
    float s = v.x * v.x + v.y * v.y;
    #pragma unroll
    for (int o = 32; o; o >>= 1) s += __shfl_down(s, o, 64);
    if (l == 0) e2[k] = s;
}

// ---------------- K1: fragment-ordered -2*emb (f16), e2+512 hi/lo fold in step 8 ----------------
__global__ __launch_bounds__(256) void k_prep(const float* __restrict__ emb, const float* __restrict__ e2,
                                              _Float16* __restrict__ embFh) {
    int tid = blockIdx.x * 256 + threadIdx.x;   // < 147456 = 8192*18
    int m = tid / 18, r = tid % 18;
    int s = r >> 1, h = r & 1;
    f16x8 hv;
    #pragma unroll
    for (int j = 0; j < 8; ++j) hv[j] = (_Float16)0.0f;
    if (s < 8) {
        int c0 = s * 16 + h * 8;
        const float4 a = *(const float4*)&emb[(size_t)m * 128 + c0];
        const float4 b = *(const float4*)&emb[(size_t)m * 128 + c0 + 4];
        float vals[8] = {a.x, a.y, a.z, a.w, b.x, b.y, b.z, b.w};
        #pragma unroll
        for (int j = 0; j < 8; ++j) hv[j] = (_Float16)(-2.0f * vals[j]);
    } else if (h == 0) {
        float v = e2[m] + 512.0f;    // offset keeps packed values > 0 (z2 dropped)
        _Float16 eh = (_Float16)v;
        hv[0] = eh;                  // x B8[0]=1
        hv[1] = (_Float16)(v - (float)eh);   // x B8[1]=1
    }
    size_t base = (((size_t)(m >> 5) * 9 + s) * 64 + (m & 31) + h * 32) * 8;
    *(f16x8*)&embFh[base] = hv;
}

// ---------------- K2: fused linear + MFMA + packed group-min top-6 ----------------
// LDS-staged A-tiles: per round the 4 waves cooperatively global_load_lds 4 ctiles
// (36864 B, double-buffered in the dead As/Xs region). Wave w computes ctile 4r+w
// against B0 and B1 (18 MFMA, two dist-2 chains), tail deferred one round (r3 win).
// Counted vmcnt(9) + raw s_barrier pipeline: staging flows one full round ahead in
// the HW queue, consuming no VGPRs -> compiler cannot sink loads to point-of-use.
__global__ __launch_bounds__(256, 2) void k_main(
    const float* __restrict__ x, const float* __restrict__ Wl, const float* __restrict__ bl,
    const _Float16* __restrict__ embFh,
    float* __restrict__ zws, float4* __restrict__ cand)
{
    // smem map: [0..73728) = stage dbuf (phase 3) / As(33792)+Xs(16896) (phases 1-2)
    //           / Ms merge scratch 12288 (phase 4); [73728..74752) = z2p
    __shared__ __align__(16) char smem[74752];
    float* As  = (float*)smem;                 // z [p][c], pitch 132 (phases 1-2)
    float* Xs  = (float*)(smem + 33792);       // x staging (phase 1)
    float* z2p = (float*)(smem + 73728);       // z^2 partials [p][ig]

    const int t  = threadIdx.x;
    const int n0 = blockIdx.x * 64;
    const int b  = n0 >> 10;
    const int hw0 = n0 & 1023;

    // ===== Phase 1: z for 64 pixels =====
    {
        const int p = t & 63, ig = t >> 6;
        float accz[32];
        const float4* bl4 = (const float4*)(bl + ig * 32);
        #pragma unroll
        for (int q = 0; q < 8; ++q) {
            float4 v = bl4[q];
            accz[4*q+0] = v.x; accz[4*q+1] = v.y; accz[4*q+2] = v.z; accz[4*q+3] = v.w;
        }
        for (int hf = 0; hf < 2; ++hf) {
            __syncthreads();
            for (int r = 0; r < 16; ++r) {
                int lin = r * 256 + t;
                int cc = lin >> 6, pp = lin & 63;
                Xs[cc * 66 + pp] = x[(size_t)(b * 128 + hf * 64 + cc) * 1024 + hw0 + pp];
            }
            __syncthreads();
            for (int cc4 = 0; cc4 < 16; ++cc4) {
                float xv0 = Xs[(cc4*4+0) * 66 + p];
                float xv1 = Xs[(cc4*4+1) * 66 + p];
                float xv2 = Xs[(cc4*4+2) * 66 + p];
                float xv3 = Xs[(cc4*4+3) * 66 + p];
                #pragma unroll
                for (int ii = 0; ii < 32; ++ii) {
                    const float4 w4 = *(const float4*)&Wl[(size_t)(ig*32+ii) * 128 + hf*64 + cc4*4];
                    float a = accz[ii];
                    a = fmaf(w4.x, xv0, a);
                    a = fmaf(w4.y, xv1, a);
                    a = fmaf(w4.z, xv2, a);
                    a = fmaf(w4.w, xv3, a);
                    accz[ii] = a;
                }
            }
        }
        float ssq = 0.f;
        float4* ao = (float4*)&As[p * 132 + ig * 32];
        float4* zo = (float4*)(zws + (size_t)(n0 + p) * 128 + ig * 32);
        #pragma unroll
        for (int q = 0; q < 8; ++q) {
            float4 v = make_float4(accz[4*q+0], accz[4*q+1], accz[4*q+2], accz[4*q+3]);
            ao[q] = v;
            zo[q] = v;
            ssq = fmaf(v.x, v.x, fmaf(v.y, v.y, fmaf(v.z, v.z, fmaf(v.w, v.w, ssq))));
        }
        z2p[p * 4 + ig] = ssq;
    }
    __syncthreads();

    // ===== Phase 2: B fragments (z f16) + constant fold step =====
    const int l = t & 63, w = t >> 6;
    const int half = l >> 5, pcol = l & 31;
    f16x8 B0[9], B1[9];
    #pragma unroll
    for (int nt = 0; nt < 2; ++nt) {
        int p = nt * 32 + pcol;
        #pragma unroll
        for (int s = 0; s < 8; ++s) {
            const float* zp = &As[p * 132 + s * 16 + half * 8];
            float4 v0 = *(const float4*)zp;
            float4 v1 = *(const float4*)(zp + 4);
            float vals[8] = {v0.x, v0.y, v0.z, v0.w, v1.x, v1.y, v1.z, v1.w};
            f16x8 hh;
            #pragma unroll
            for (int j2 = 0; j2 < 8; ++j2) hh[j2] = (_Float16)vals[j2];
            if (nt == 0) B0[s] = hh; else B1[s] = hh;
        }
    }
    {
        f16x8 b8;
        #pragma unroll
        for (int j2 = 0; j2 < 8; ++j2) b8[j2] = (_Float16)0.0f;
        if (half == 0) { b8[0] = (_Float16)1.0f; b8[1] = (_Float16)1.0f; }
        B0[8] = b8; B1[8] = b8;
    }
    __syncthreads();   // As dead; stage region free

    // ===== Phase 3: LDS-staged K-loop, 64 rounds x 4 ctiles, deferred tails =====
    auto tree16 = [](const f32x16& v) -> float {
        float a = min3f(v[0], v[1], v[2]);
        float bb = min3f(v[3], v[4], v[5]);
        float c = min3f(v[6], v[7], v[8]);
        float d = min3f(v[9], v[10], v[11]);
        float e = min3f(v[12], v[13], v[14]);
        float f = min3f(a, bb, c);
        float g = min3f(d, e, v[15]);
        return fminf(f, g);
    };

    float gv[6] = {3e38f, 3e38f, 3e38f, 3e38f, 3e38f, 3e38f};   // B0 tile: px = pcol
    float hv[6] = {3e38f, 3e38f, 3e38f, 3e38f, 3e38f, 3e38f};   // B1 tile: px = 32+pcol

    #define TAIL2(A0_, A1_, TILE_) { \
        float m0_ = tree16(A0_), m1_ = tree16(A1_); \
        uint32_t id_ = (uint32_t)((((TILE_) << 1) | half)); \
        ins6(packmin(m0_, id_), gv); \
        ins6(packmin(m1_, id_), hv); \
    }

    // Round r: read slot w of buf[r&1]; lgkm(0)+bar; stage round r+2 into same buf;
    // 18 MFMA; deferred tail of round r-1; vmcnt(9)+bar (round r+1's buffer ready).
    #define RND(R_, C0_, C1_, O0_, O1_, DT_) { \
        const int p_ = (R_) & 1; \
        const char* rb_ = smem + p_ * 36864 + w * 9216 + (l << 4); \
        f16x8 A_[9]; \
        _Pragma("unroll") \
        for (int s_ = 0; s_ < 9; ++s_) A_[s_] = *(const f16x8*)(rb_ + (s_ << 10)); \
        asm volatile("s_waitcnt lgkmcnt(0)" ::: "memory"); \
        __builtin_amdgcn_sched_barrier(0); \
        __builtin_amdgcn_s_barrier(); \
        __builtin_amdgcn_sched_barrier(0); \
        { \
            const char* gs_ = (const char*)embFh + (size_t)(((R_) + 2) & 63) * 36864; \
            char* ls_ = smem + p_ * 36864; \
            _Pragma("unroll") \
            for (int k_ = 0; k_ < 9; ++k_) { \
                const int off_ = ((k_ * 4 + w) << 10) + (l << 4); \
                gload16(gs_ + off_, ls_ + off_); \
            } \
        } \
        C0_ = (f32x16){}; C1_ = (f32x16){}; \
        _Pragma("unroll") \
        for (int s_ = 0; s_ < 9; ++s_) { \
            C0_ = __builtin_amdgcn_mfma_f32_32x32x16_f16(A_[s_], B0[s_], C0_, 0, 0, 0); \
            C1_ = __builtin_amdgcn_mfma_f32_32x32x16_f16(A_[s_], B1[s_], C1_, 0, 0, 0); \
        } \
        if (DT_) TAIL2(O0_, O1_, 4 * ((R_) - 1) + w); \
        asm volatile("s_waitcnt vmcnt(9)" ::: "memory"); \
        __builtin_amdgcn_sched_barrier(0); \
        __builtin_amdgcn_s_barrier(); \
        __builtin_amdgcn_sched_barrier(0); \
    }

    // prologue: stage rounds 0 (buf0) and 1 (buf1)
    #pragma unroll
    for (int m = 0; m < 2; ++m) {
        const char* gs = (const char*)embFh + (size_t)m * 36864;
        char* ls = smem + m * 36864;
        #pragma unroll
        for (int k = 0; k < 9; ++k) {
            const int off = ((k * 4 + w) << 10) + (l << 4);
            gload16(gs + off, ls + off);
        }
    }
    asm volatile("s_waitcnt vmcnt(9)" ::: "memory");
    __builtin_amdgcn_sched_barrier(0);
    __builtin_amdgcn_s_barrier();
    __builtin_amdgcn_sched_barrier(0);

    f32x16 P0 = {}, P1 = {}, Q0 = {}, Q1 = {};
    RND(0, P0, P1, Q0, Q1, 0);
    #pragma unroll 1
    for (int rp = 0; rp < 31; ++rp) {
        const int r = 2 * rp + 1;
        RND(r,     Q0, Q1, P0, P1, 1);
        RND(r + 1, P0, P1, Q0, Q1, 1);
    }
    RND(63, Q0, Q1, P0, P1, 1);
    TAIL2(Q0, Q1, 4 * 63 + w);

    #undef RND
    #undef TAIL2

    asm volatile("s_waitcnt vmcnt(0)" ::: "memory");
    __syncthreads();

    // ===== Phase 4: cross-wave merge per pixel, write cand (6 groups + z2) =====
    float* Ms = (float*)smem;   // [64 px][8 slots][6] = 12288 B (stage region dead)
    const int slot = (w << 1) | half;
    #pragma unroll
    for (int q = 0; q < 6; ++q) {
        Ms[(pcol * 8 + slot) * 6 + q] = gv[q];
        Ms[((32 + pcol) * 8 + slot) * 6 + q] = hv[q];
    }
    __syncthreads();
    if (t < 64) {
        float v6[6] = {3e38f, 3e38f, 3e38f, 3e38f, 3e38f, 3e38f};
        #pragma unroll
        for (int s = 0; s < 48; ++s) ins6(Ms[t * 48 + s], v6);
        float z2 = z2p[t*4+0] + z2p[t*4+1] + z2p[t*4+2] + z2p[t*4+3];
        cand[(size_t)(n0 + t) * 2 + 0] = make_float4(v6[0], v6[1], v6[2], v6[3]);
        cand[(size_t)(n0 + t) * 2 + 1] = make_float4(v6[4], v6[5], z2, 0.f);
    }
}

// ---------------- K3: early-exit exact fp32 over candidate groups ----------------
// Packed id decode: id = bits[8:0], tile = id>>1, half = id&1;
// group codes m = tile*32 + half*4 + {(c&3) + 8*(c>>2)}.
// Flags: !safe -> rlistA (parallel full scan); near-tie -> rlistB (fp64 pair arb).
__global__ __launch_bounds__(256) void k_rec(
    const float* __restrict__ zws, const float* __restrict__ emb,
    const float4* __restrict__ cand, int* __restrict__ idxws,
    float* __restrict__ out_idxf, float* __restrict__ losssum,
    int* __restrict__ rlistA, int* __restrict__ rcntA,
    int* __restrict__ rlistB, int* __restrict__ rcntB)
{
    __shared__ float lred[16];
    const int t = threadIdx.x;
    const int pl = t >> 4, j = t & 15;
    const int n = blockIdx.x * 16 + pl;

    const float4 za = *(const float4*)&zws[(size_t)n * 128 + j * 8];
    const float4 zb = *(const float4*)&zws[(size_t)n * 128 + j * 8 + 4];
    const float4 c0 = cand[(size_t)n * 2 + 0];
    const float4 c1 = cand[(size_t)n * 2 + 1];
    const float pv[6] = {c0.x, c0.y, c0.z, c0.w, c1.x, c1.y};
    const float pbase = c1.z - 512.0f;   // d = packed + pbase

    float d1 = 3e38f, d2 = 3e38f; int i1 = 0x7fffffff, i2 = 0x7fffffff;
    bool safe = false;
    float lastgmin = 0.f;
    for (int q = 0; q < 6; ++q) {
        uint32_t bits = __float_as_uint(pv[q]);
        float gmin = __uint_as_float(bits & 0xFFFFFE00u);
        lastgmin = gmin;
        if (gmin >= d1 - pbase + EPS_STOP) { safe = true; break; }
        const int mbase = (int)((bits >> 1) & 255u) * 32 + (int)((bits & 1u) << 2); // tile*32 + half*4
        #pragma unroll
        for (int c = 0; c < 16; ++c) {
            int m = mbase + (c & 3) + 8 * (c >> 2);
            const float4 ea = *(const float4*)&emb[(size_t)m * 128 + j * 8];
            const float4 eb = *(const float4*)&emb[(size_t)m * 128 + j * 8 + 4];
            float da0 = za.x - ea.x, da1 = za.y - ea.y, da2 = za.z - ea.z, da3 = za.w - ea.w;
            float db0 = zb.x - eb.x, db1 = zb.y - eb.y, db2 = zb.z - eb.z, db3 = zb.w - eb.w;
            float s = da0*da0; s = fmaf(da1, da1, s); s = fmaf(da2, da2, s); s = fmaf(da3, da3, s);
            s = fmaf(db0, db0, s); s = fmaf(db1, db1, s); s = fmaf(db2, db2, s); s = fmaf(db3, db3, s);
            s += __shfl_xor(s, 1, 16);
            s += __shfl_xor(s, 2, 16);
            s += __shfl_xor(s, 4, 16);
            s += __shfl_xor(s, 8, 16);
            if (s < d1 || (s == d1 && m < i1)) { d2 = d1; i2 = i1; d1 = s; i1 = m; }
            else if (s < d2) { d2 = s; i2 = m; }
        }
    }
    if (!safe && lastgmin >= d1 - pbase + EPS_STOP) safe = true;  // post-check vs pv[5]

    if (j == 0) {
        idxws[n] = i1;
        out_idxf[n] = (float)i1;
        if (!safe) {
            int s = atomicAdd(rcntA, 1);
            if (s < RCAPA) rlistA[s] = n;
        } else if ((d2 - d1) < TAUF) {
            int s = atomicAdd(rcntB, 1);
            if (s < RCAP) { int4 v4 = make_int4(n, i1, i2, 0); ((int4*)rlistB)[s] = v4; }
        }
        lred[pl] = d1;
    }
    __syncthreads();
    if (t == 0) {
        float ls = 0.f;
        #pragma unroll
        for (int q = 0; q < 16; ++q) ls += lred[q];
        atomicAdd(losssum, ls);
    }
}

// ---------------- K4a: parallel full scan for !safe pixels ----------------
// 32 chunk-blocks per pixel, 256 codes/chunk; 16 lanes/code coalesced; fp64 accum.
__global__ __launch_bounds__(256) void k_scanp(
    const float* __restrict__ zws, const float* __restrict__ emb,
    const int* __restrict__ rcntA, const int* __restrict__ rlistA,
    double* __restrict__ scand, int* __restrict__ scani)
{
    int cnt = *rcntA; if (cnt > RCAPA) cnt = RCAPA;
    const int t = threadIdx.x;
    const int chunk = blockIdx.x & 31;
    const int gi = t >> 4, j = t & 15;
    __shared__ double sd[16];
    __shared__ int si[16];
    for (int e = blockIdx.x >> 5; e < cnt; e += 64) {
        const int n = rlistA[e];
        const float4 za = *(const float4*)&zws[(size_t)n * 128 + j * 8];
        const float4 zb = *(const float4*)&zws[(size_t)n * 128 + j * 8 + 4];
        double best = 1e300; int bi = 0x7fffffff;
        const int kbase = chunk * 256 + gi * 16;
        for (int c = 0; c < 16; ++c) {
            const int m = kbase + c;
            const float4 ea = *(const float4*)&emb[(size_t)m * 128 + j * 8];
            const float4 eb = *(const float4*)&emb[(size_t)m * 128 + j * 8 + 4];
            double s = 0.0, d;
            d = (double)za.x - (double)ea.x; s += d * d;
            d = (double)za.y - (double)ea.y; s += d * d;
            d = (double)za.z - (double)ea.z; s += d * d;
            d = (double)za.w - (double)ea.w; s += d * d;
            d = (double)zb.x - (double)eb.x; s += d * d;
            d = (double)zb.y - (double)eb.y; s += d * d;
            d = (double)zb.z - (double)eb.z; s += d * d;
            d = (double)zb.w - (double)eb.w; s += d * d;
            s += __shfl_xor(s, 1, 16);
            s += __shfl_xor(s, 2, 16);
            s += __shfl_xor(s, 4, 16);
            s += __shfl_xor(s, 8, 16);
            if (s < best) { best = s; bi = m; }   // m strictly increasing -> first-index
        }
        __syncthreads();
        if (j == 0) { sd[gi] = best; si[gi] = bi; }
        __syncthreads();
        if (t == 0) {
            double b = sd[0]; int ib = si[0];
            #pragma unroll
            for (int q = 1; q < 16; ++q)
                if (sd[q] < b || (sd[q] == b && si[q] < ib)) { b = sd[q]; ib = si[q]; }
            scand[e * 32 + chunk] = b;
            scani[e * 32 + chunk] = ib;
        }
    }
}

// ---------------- K4b: merge 32 chunk results per !safe pixel ----------------
__global__ __launch_bounds__(64) void k_mergeA(
    const int* __restrict__ rcntA, const int* __restrict__ rlistA,
    const double* __restrict__ scand, const int* __restrict__ scani,
    int* __restrict__ idxws, float* __restrict__ out_idxf)
{
    int cnt = *rcntA; if (cnt > RCAPA) cnt = RCAPA;
    const int t = threadIdx.x;
    for (int e = blockIdx.x; e < cnt; e += gridDim.x) {
        double b = 1e300; int ib = 0x7fffffff;
        if (t < 32) { b = scand[e * 32 + t]; ib = scani[e * 32 + t]; }
        #pragma unroll
        for (int o = 16; o; o >>= 1) {
            double ob = __shfl_down(b, o, 64);
            int oi = __shfl_down(ib, o, 64);
            if (ob < b || (ob == b && oi < ib)) { b = ob; ib = oi; }
        }
        if (t == 0) { int n = rlistA[e]; idxws[n] = ib; out_idxf[n] = (float)ib; }
    }
}

// ---------------- K4c: fp64 pair arbitration for near-tie pixels ----------------
__global__ __launch_bounds__(128) void k_pairB(
    const float* __restrict__ x, const float* __restrict__ Wl, const float* __restrict__ bl,
    const float* __restrict__ emb, const int* __restrict__ rcntB, const int* __restrict__ rlistB,
    int* __restrict__ idxws, float* __restrict__ out_idxf)
{
    __shared__ double xs[128];
    __shared__ double red[128];
    int cnt = *rcntB; if (cnt > RCAP) cnt = RCAP;
    const int t = threadIdx.x;
    for (int e = blockIdx.x; e < cnt; e += gridDim.x) {
        const int4 v = ((const int4*)rlistB)[e];
        const int n = v.x, c1 = v.y, c2 = v.z;
        const int b = n >> 10, hw = n & 1023;
        __syncthreads();
        xs[t] = (double)x[(size_t)(b * 128 + t) * 1024 + hw];
        __syncthreads();
        double z = (double)bl[t];
        for (int c = 0; c < 128; ++c) z = fma((double)Wl[(size_t)t * 128 + c], xs[c], z);
        double d1v, d2v;
        double da = z - (double)emb[(size_t)c1 * 128 + t];
        red[t] = da * da; __syncthreads();
        for (int o = 64; o; o >>= 1) { if (t < o) red[t] += red[t + o]; __syncthreads(); }
        d1v = red[0]; __syncthreads();
        double db = z - (double)emb[(size_t)c2 * 128 + t];
        red[t] = db * db; __syncthreads();
        for (int o = 64; o; o >>= 1) { if (t < o) red[t] += red[t + o]; __syncthreads(); }
        d2v = red[0];
        if (t == 0) {
            int win = (d2v < d1v || (d2v == d1v && c2 < c1)) ? c2 : c1;
            idxws[n] = win;
            out_idxf[n] = (float)win;
        }
        __syncthreads();
    }
}

// ---------------- K5: gather + transpose + histogram ----------------
__global__ __launch_bounds__(256) void k_out(
    const float* __restrict__ emb, const int* __restrict__ idxws,
    float* __restrict__ outp /* d_out + 1 */, float* __restrict__ counts)
{
    const int t = threadIdx.x;
    const int b = blockIdx.x >> 2, h0 = (blockIdx.x & 3) << 3;
    const int n = b * 1024 + h0 * 32 + t;
    const int id = idxws[n];
    atomicAdd(&counts[id], 1.0f);
    const float4* ep = (const float4*)&emb[(size_t)id * 128];
    float* ob = outp + (size_t)b * 131072 + h0 * 32 + t;
    #pragma unroll 4
    for (int c4 = 0; c4 < 32; ++c4) {
        float4 v = ep[c4];
        ob[(c4 * 4 + 0) * 1024] = v.x;
        ob[(c4 * 4 + 1) * 1024] = v.y;
        ob[(c4 * 4 + 2) * 1024] = v.z;
        ob[(c4 * 4 + 3) * 1024] = v.w;
    }
}

// ---------------- K6: finalize loss + perplexity ----------------
__global__ __launch_bounds__(256) void k_final(
    const float* __restrict__ counts, const float* __restrict__ losssum, float* __restrict__ d_out)
{
    const int t = threadIdx.x;
    float ent = 0.f;
    for (int k = t; k < KCB; k += 256) {
        float p = counts[k] * (1.0f / 32768.0f);
        ent -= p * logf(p + 1e-10f);
    }
    #pragma unroll
    for (int o = 32; o; o >>= 1) ent += __shfl_down(ent, o, 64);
    __shared__ float wred[4];
    if ((t & 63) == 0) wred[t >> 6] = ent;
    __syncthreads();
    if (t == 0) {
        float e = wred[0] + wred[1] + wred[2] + wred[3];
        d_out[0] = 1.25f * (*losssum) * (1.0f / 4194304.0f);
        d_out[OUT_OFF_PERP] = expf(e);
    }
}

extern "C" void kernel_launch(void* const* d_in, const int* in_sizes, int n_in,
                              void* d_out, int out_size, void* d_ws, size_t ws_size,
                              hipStream_t stream) {
    (void)in_sizes; (void)n_in; (void)out_size; (void)ws_size;
    const float* x   = (const float*)d_in[0];
    const float* Wl  = (const float*)d_in[1];
    const float* bl  = (const float*)d_in[2];
    const float* emb = (const float*)d_in[3];
    float* out = (float*)d_out;
    char*  ws  = (char*)d_ws;

    _Float16* embFh = (_Float16*)(ws + WS_EMBFH);
    float* e2      = (float*)(ws + WS_E2);
    float* zws     = (float*)(ws + WS_ZWS);
    float4* cand   = (float4*)(ws + WS_CAND);
    int*   idxws   = (int*)  (ws + WS_IDX);
    int*   rlistA  = (int*)  (ws + WS_RLISTA);
    int*   rlistB  = (int*)  (ws + WS_RLISTB);
    double* scand  = (double*)(ws + WS_SCAND);
    int*   scani   = (int*)  (ws + WS_SCANI);
    float* counts  = (float*)(ws + WS_COUNTS);
    float* losssum = (float*)(ws + WS_LOSS);
    int*   rcntA   = (int*)  (ws + WS_RCNTA);
    int*   rcntB   = (int*)  (ws + WS_RCNTB);

    hipMemsetAsync(ws + WS_ZERO_OFF, 0, WS_ZERO_LEN, stream);

    k_e2<<<KCB / 4, 256, 0, stream>>>(emb, e2);
    k_prep<<<576, 256, 0, stream>>>(emb, e2, embFh);
    k_main<<<NPIX / 64, 256, 0, stream>>>(x, Wl, bl, embFh, zws, cand);
    k_rec<<<NPIX / 16, 256, 0, stream>>>(zws, emb, cand, idxws, out + OUT_OFF_IDX,
                                         losssum, rlistA, rcntA, rlistB, rcntB);
    k_scanp<<<2048, 256, 0, stream>>>(zws, emb, rcntA, rlistA, scand, scani);
    k_mergeA<<<32, 64, 0, stream>>>(rcntA, rlistA, scand, scani, idxws, out + OUT_OFF_IDX);
    k_pairB<<<256, 128, 0, stream>>>(x, Wl, bl, emb, rcntB, rlistB, idxws, out + OUT_OFF_IDX);
    k_out<<<128, 256, 0, stream>>>(emb, idxws, out + OUT_OFF_OUT, counts);
    k_final<<<1, 256, 0, stream>>>(counts, losssum, out);
}

// Round 6
// 296.891 us; speedup vs baseline: 1.1060x; 1.0272x over previous
//
#include <hip/hip_runtime.h>
#include <hip/hip_bf16.h>
#include <float.h>

// Problem constants
#define NPIX   32768      // B*H*W
#define CDIM   128
#define KCB    8192
#define EPS_STOP 0.30f    // mask quant (0.031) + f16-dot error bound
#define TAUF   0.012f     // exact fp32 gap guard -> fp64 arbitration
#define RCAP   8192
#define RCAPA  2048

typedef _Float16 f16x8 __attribute__((ext_vector_type(8)));
typedef float    f32x16 __attribute__((ext_vector_type(16)));

// ws layout (bytes)
#define WS_EMBFH   0           // 2,359,296
#define WS_E2      2359296     // 32,768
#define WS_ZWS     2392064     // 16,777,216
#define WS_CAND    19169280    // 1,048,576
#define WS_IDX     20217856    // 131,072
#define WS_RLISTA  20348928    // 32,768 (cap 2048 used)
#define WS_RLISTB  20381696    // 131,072 (8192 * int4)
#define WS_SCAND   20512768    // 524,288 (2048*32 double)
#define WS_SCANI   21037056    // 262,144 (2048*32 int)
#define WS_COUNTS  21299200    // 32,768
#define WS_LOSS    21331968    // 4
#define WS_RCNTA   21331972    // 4
#define WS_RCNTB   21331976    // 4
#define WS_ZERO_OFF 21299200
#define WS_ZERO_LEN 32780

// d_out layout (f32): [0]=loss, [1..4194304]=out BCHW, [4194305]=perplexity, [4194306..]=idx
#define OUT_OFF_OUT  1
#define OUT_OFF_PERP 4194305
#define OUT_OFF_IDX  4194306

__device__ __forceinline__ float min3f(float a, float b, float c) {
    return fminf(fminf(a, b), c);   // -> v_min3_f32
}

__device__ __forceinline__ void ins6(float f, float v[6]) {
    float a = fmaxf(v[0], f); v[0] = fminf(v[0], f);
    float b = fmaxf(v[1], a); v[1] = fminf(v[1], a);
    a = fmaxf(v[2], b); v[2] = fminf(v[2], b);
    b = fmaxf(v[3], a); v[3] = fminf(v[3], a);
    a = fmaxf(v[4], b); v[4] = fminf(v[4], b);
    v[5] = fminf(v[5], a);
}

__device__ __forceinline__ float packmin(float m, uint32_t id) {
    return __uint_as_float((__float_as_uint(m) & 0xFFFFFE00u) | id);
}

// ---------------- K0: e2[k] = sum_c emb[k][c]^2 ----------------
__global__ __launch_bounds__(256) void k_e2(const float* __restrict__ emb, float* __restrict__ e2) {
    int t = threadIdx.x;
    int wv = t >> 6, l = t & 63;
    int k = blockIdx.x * 4 + wv;
    const float2 v = *(const float2*)&emb[(size_t)k * 128 + l * 2];
    float s = v.x * v.x + v.y * v.y;
    #pragma unroll
    for (int o = 32; o; o >>= 1) s += __shfl_down(s, o, 64);
    if (l == 0) e2[k] = s;
}

// ---------------- K1: fragment-ordered -2*emb (f16), e2+512 hi/lo fold in step 8 ----------------
__global__ __launch_bounds__(256) void k_prep(const float* __restrict__ emb, const float* __restrict__ e2,
                                              _Float16* __restrict__ embFh) {
    int tid = blockIdx.x * 256 + threadIdx.x;   // < 147456 = 8192*18
    int m = tid / 18, r = tid % 18;
    int s = r >> 1, h = r & 1;
    f16x8 hv;
    #pragma unroll
    for (int j = 0; j < 8; ++j) hv[j] = (_Float16)0.0f;
    if (s < 8) {
        int c0 = s * 16 + h * 8;
        const float4 a = *(const float4*)&emb[(size_t)m * 128 + c0];
        const float4 b = *(const float4*)&emb[(size_t)m * 128 + c0 + 4];
        float vals[8] = {a.x, a.y, a.z, a.w, b.x, b.y, b.z, b.w};
        #pragma unroll
        for (int j = 0; j < 8; ++j) hv[j] = (_Float16)(-2.0f * vals[j]);
    } else if (h == 0) {
        float v = e2[m] + 512.0f;    // offset keeps packed values > 0 (z2 dropped)
        _Float16 eh = (_Float16)v;
        hv[0] = eh;                  // x B8[0]=1
        hv[1] = (_Float16)(v - (float)eh);   // x B8[1]=1
    }
    size_t base = (((size_t)(m >> 5) * 9 + s) * 64 + (m & 31) + h * 32) * 8;
    *(f16x8*)&embFh[base] = hv;
}

// ---------------- K2: fused linear + MFMA + packed group-min top-6 ----------------
// r3 structure (proven best): software-pipelined reduction — each tile's tail
// (tree16+ins6) is deferred until AFTER the next tile's 18-MFMA burst has issued.
// Ping-pong acc sets (e0/e1 vs o0/o1), named regs only. No K-loop barriers ->
// waves desynchronize; s_setprio(1) around bursts biases the CU scheduler
// toward MFMA-issuing waves (T5 regime: role-diverse waves).
__global__ __launch_bounds__(256, 2) void k_main(
    const float* __restrict__ x, const float* __restrict__ Wl, const float* __restrict__ bl,
    const _Float16* __restrict__ embFh,
    float* __restrict__ zws, float4* __restrict__ cand)
{
    __shared__ __align__(16) float As[64 * 132];   // z [p][c], pitch 132
    __shared__ __align__(16) float Xs[64 * 66];    // x staging / merge scratch
    __shared__ float z2p[256];                      // z^2 partials [p][ig]

    const int t  = threadIdx.x;
    const int n0 = blockIdx.x * 64;
    const int b  = n0 >> 10;
    const int hw0 = n0 & 1023;

    // ===== Phase 1: z for 64 pixels =====
    {
        const int p = t & 63, ig = t >> 6;
        float accz[32];
        const float4* bl4 = (const float4*)(bl + ig * 32);
        #pragma unroll
        for (int q = 0; q < 8; ++q) {
            float4 v = bl4[q];
            accz[4*q+0] = v.x; accz[4*q+1] = v.y; accz[4*q+2] = v.z; accz[4*q+3] = v.w;
        }
        for (int hf = 0; hf < 2; ++hf) {
            __syncthreads();
            for (int r = 0; r < 16; ++r) {
                int lin = r * 256 + t;
                int cc = lin >> 6, pp = lin & 63;
                Xs[cc * 66 + pp] = x[(size_t)(b * 128 + hf * 64 + cc) * 1024 + hw0 + pp];
            }
            __syncthreads();
            for (int cc4 = 0; cc4 < 16; ++cc4) {
                float xv0 = Xs[(cc4*4+0) * 66 + p];
                float xv1 = Xs[(cc4*4+1) * 66 + p];
                float xv2 = Xs[(cc4*4+2) * 66 + p];
                float xv3 = Xs[(cc4*4+3) * 66 + p];
                #pragma unroll
                for (int ii = 0; ii < 32; ++ii) {
                    const float4 w4 = *(const float4*)&Wl[(size_t)(ig*32+ii) * 128 + hf*64 + cc4*4];
                    float a = accz[ii];
                    a = fmaf(w4.x, xv0, a);
                    a = fmaf(w4.y, xv1, a);
                    a = fmaf(w4.z, xv2, a);
                    a = fmaf(w4.w, xv3, a);
                    accz[ii] = a;
                }
            }
        }
        float ssq = 0.f;
        float4* ao = (float4*)&As[p * 132 + ig * 32];
        float4* zo = (float4*)(zws + (size_t)(n0 + p) * 128 + ig * 32);
        #pragma unroll
        for (int q = 0; q < 8; ++q) {
            float4 v = make_float4(accz[4*q+0], accz[4*q+1], accz[4*q+2], accz[4*q+3]);
            ao[q] = v;
            zo[q] = v;
            ssq = fmaf(v.x, v.x, fmaf(v.y, v.y, fmaf(v.z, v.z, fmaf(v.w, v.w, ssq))));
        }
        z2p[p * 4 + ig] = ssq;
    }
    __syncthreads();

    // ===== Phase 2: B fragments (z f16) + constant fold step =====
    const int l = t & 63, w = t >> 6;
    const int half = l >> 5, pcol = l & 31;
    f16x8 B0[9], B1[9];
    #pragma unroll
    for (int nt = 0; nt < 2; ++nt) {
        int p = nt * 32 + pcol;
        #pragma unroll
        for (int s = 0; s < 8; ++s) {
            const float* zp = &As[p * 132 + s * 16 + half * 8];
            float4 v0 = *(const float4*)zp;
            float4 v1 = *(const float4*)(zp + 4);
            float vals[8] = {v0.x, v0.y, v0.z, v0.w, v1.x, v1.y, v1.z, v1.w};
            f16x8 hh;
            #pragma unroll
            for (int j2 = 0; j2 < 8; ++j2) hh[j2] = (_Float16)vals[j2];
            if (nt == 0) B0[s] = hh; else B1[s] = hh;
        }
    }
    {
        f16x8 b8;
        #pragma unroll
        for (int j2 = 0; j2 < 8; ++j2) b8[j2] = (_Float16)0.0f;
        if (half == 0) { b8[0] = (_Float16)1.0f; b8[1] = (_Float16)1.0f; }
        B0[8] = b8; B1[8] = b8;
    }

    // ===== Phase 3: K-loop, deferred-tail pipeline =====
    auto tree16 = [](const f32x16& v) -> float {
        float a = min3f(v[0], v[1], v[2]);
        float bb = min3f(v[3], v[4], v[5]);
        float c = min3f(v[6], v[7], v[8]);
        float d = min3f(v[9], v[10], v[11]);
        float e = min3f(v[12], v[13], v[14]);
        float f = min3f(a, bb, c);
        float g = min3f(d, e, v[15]);
        return fminf(f, g);
    };

    float gv[6] = {3e38f, 3e38f, 3e38f, 3e38f, 3e38f, 3e38f};   // tile0: px = pcol
    float hv[6] = {3e38f, 3e38f, 3e38f, 3e38f, 3e38f, 3e38f};   // tile1: px = 32+pcol
    const f16x8* Ahp = (const f16x8*)embFh;
    f16x8 aE[9], aO[9];
    {
        const f16x8* P = Ahp + (size_t)w * 576 + l;
        #pragma unroll
        for (int s = 0; s < 9; ++s) aE[s] = P[s * 64];
    }
    {
        const f16x8* P = Ahp + (size_t)(w + 4) * 576 + l;
        #pragma unroll
        for (int s = 0; s < 9; ++s) aO[s] = P[s * 64];
    }

    f32x16 e0, e1, o0, o1;
    uint32_t idv = (uint32_t)((w << 1) | half);

    // prologue: burst even tile w
    e0 = {}; e1 = {};
    __builtin_amdgcn_s_setprio(1);
    #pragma unroll
    for (int s = 0; s < 9; ++s) {
        e0 = __builtin_amdgcn_mfma_f32_32x32x16_f16(aE[s], B0[s], e0, 0, 0, 0);
        e1 = __builtin_amdgcn_mfma_f32_32x32x16_f16(aE[s], B1[s], e1, 0, 0, 0);
    }
    __builtin_amdgcn_s_setprio(0);

    for (int it = 0; it < 31; ++it) {
        const int g = w + it * 8;
        {   // refill aE <- tile g+8 (consumed by burstE at end of this iteration)
            const f16x8* P = Ahp + (size_t)(g + 8) * 576 + l;
            #pragma unroll
            for (int s = 0; s < 9; ++s) aE[s] = P[s * 64];
        }
        // burst odd tile g+4
        o0 = {}; o1 = {};
        __builtin_amdgcn_s_setprio(1);
        #pragma unroll
        for (int s = 0; s < 9; ++s) {
            o0 = __builtin_amdgcn_mfma_f32_32x32x16_f16(aO[s], B0[s], o0, 0, 0, 0);
            o1 = __builtin_amdgcn_mfma_f32_32x32x16_f16(aO[s], B1[s], o1, 0, 0, 0);
        }
        __builtin_amdgcn_s_setprio(0);
        // deferred tail: even tile g (burst issued one burst ago)
        {
            float m0 = tree16(e0), m1 = tree16(e1);
            ins6(packmin(m0, idv), gv);
            ins6(packmin(m1, idv), hv);
        }
        {   // refill aO <- tile g+12 (consumed by burstO next iteration / epilogue)
            const f16x8* P = Ahp + (size_t)(g + 12) * 576 + l;
            #pragma unroll
            for (int s = 0; s < 9; ++s) aO[s] = P[s * 64];
        }
        // burst even tile g+8
        e0 = {}; e1 = {};
        __builtin_amdgcn_s_setprio(1);
        #pragma unroll
        for (int s = 0; s < 9; ++s) {
            e0 = __builtin_amdgcn_mfma_f32_32x32x16_f16(aE[s], B0[s], e0, 0, 0, 0);
            e1 = __builtin_amdgcn_mfma_f32_32x32x16_f16(aE[s], B1[s], e1, 0, 0, 0);
        }
        __builtin_amdgcn_s_setprio(0);
        // deferred tail: odd tile g+4
        {
            float m0 = tree16(o0), m1 = tree16(o1);
            ins6(packmin(m0, idv + 8u), gv);
            ins6(packmin(m1, idv + 8u), hv);
        }
        idv += 16u;
    }
    // epilogue: last odd tile w+252 (aO loaded at it=30), then both remaining tails
    o0 = {}; o1 = {};
    __builtin_amdgcn_s_setprio(1);
    #pragma unroll
    for (int s = 0; s < 9; ++s) {
        o0 = __builtin_amdgcn_mfma_f32_32x32x16_f16(aO[s], B0[s], o0, 0, 0, 0);
        o1 = __builtin_amdgcn_mfma_f32_32x32x16_f16(aO[s], B1[s], o1, 0, 0, 0);
    }
    __builtin_amdgcn_s_setprio(0);
    {   // tail even tile w+248
        float m0 = tree16(e0), m1 = tree16(e1);
        ins6(packmin(m0, idv), gv);
        ins6(packmin(m1, idv), hv);
    }
    {   // tail odd tile w+252
        float m0 = tree16(o0), m1 = tree16(o1);
        ins6(packmin(m0, idv + 8u), gv);
        ins6(packmin(m1, idv + 8u), hv);
    }

    // ===== Phase 4: cross-wave merge per pixel, write cand (6 groups + z2) =====
    __syncthreads();
    float* Ms = Xs;   // [64 px][8 slots][6]
    const int slot = (w << 1) | half;
    #pragma unroll
    for (int q = 0; q < 6; ++q) {
        Ms[(pcol * 8 + slot) * 6 + q] = gv[q];
        Ms[((32 + pcol) * 8 + slot) * 6 + q] = hv[q];
    }
    __syncthreads();
    if (t < 64) {
        float v6[6] = {3e38f, 3e38f, 3e38f, 3e38f, 3e38f, 3e38f};
        #pragma unroll
        for (int s = 0; s < 48; ++s) ins6(Ms[t * 48 + s], v6);
        float z2 = z2p[t*4+0] + z2p[t*4+1] + z2p[t*4+2] + z2p[t*4+3];
        cand[(size_t)(n0 + t) * 2 + 0] = make_float4(v6[0], v6[1], v6[2], v6[3]);
        cand[(size_t)(n0 + t) * 2 + 1] = make_float4(v6[4], v6[5], z2, 0.f);
    }
}

// ---------------- K3: early-exit exact fp32 over candidate groups ----------------
// Packed id decode: id = bits[8:0], tile = id>>1, half = id&1;
// group codes m = tile*32 + half*4 + {(c&3) + 8*(c>>2)}.
// Flags: !safe -> rlistA (parallel full scan); near-tie -> rlistB (fp64 pair arb).
__global__ __launch_bounds__(256) void k_rec(
    const float* __restrict__ zws, const float* __restrict__ emb,
    const float4* __restrict__ cand, int* __restrict__ idxws,
    float* __restrict__ out_idxf, float* __restrict__ losssum,
    int* __restrict__ rlistA, int* __restrict__ rcntA,
    int* __restrict__ rlistB, int* __restrict__ rcntB)
{
    __shared__ float lred[16];
    const int t = threadIdx.x;
    const int pl = t >> 4, j = t & 15;
    const int n = blockIdx.x * 16 + pl;

    const float4 za = *(const float4*)&zws[(size_t)n * 128 + j * 8];
    const float4 zb = *(const float4*)&zws[(size_t)n * 128 + j * 8 + 4];
    const float4 c0 = cand[(size_t)n * 2 + 0];
    const float4 c1 = cand[(size_t)n * 2 + 1];
    const float pv[6] = {c0.x, c0.y, c0.z, c0.w, c1.x, c1.y};
    const float pbase = c1.z - 512.0f;   // d = packed + pbase

    float d1 = 3e38f, d2 = 3e38f; int i1 = 0x7fffffff, i2 = 0x7fffffff;
    bool safe = false;
    float lastgmin = 0.f;
    for (int q = 0; q < 6; ++q) {
        uint32_t bits = __float_as_uint(pv[q]);
        float gmin = __uint_as_float(bits & 0xFFFFFE00u);
        lastgmin = gmin;
        if (gmin >= d1 - pbase + EPS_STOP) { safe = true; break; }
        const int mbase = (int)((bits >> 1) & 255u) * 32 + (int)((bits & 1u) << 2); // tile*32 + half*4
        #pragma unroll
        for (int c = 0; c < 16; ++c) {
            int m = mbase + (c & 3) + 8 * (c >> 2);
            const float4 ea = *(const float4*)&emb[(size_t)m * 128 + j * 8];
            const float4 eb = *(const float4*)&emb[(size_t)m * 128 + j * 8 + 4];
            float da0 = za.x - ea.x, da1 = za.y - ea.y, da2 = za.z - ea.z, da3 = za.w - ea.w;
            float db0 = zb.x - eb.x, db1 = zb.y - eb.y, db2 = zb.z - eb.z, db3 = zb.w - eb.w;
            float s = da0*da0; s = fmaf(da1, da1, s); s = fmaf(da2, da2, s); s = fmaf(da3, da3, s);
            s = fmaf(db0, db0, s); s = fmaf(db1, db1, s); s = fmaf(db2, db2, s); s = fmaf(db3, db3, s);
            s += __shfl_xor(s, 1, 16);
            s += __shfl_xor(s, 2, 16);
            s += __shfl_xor(s, 4, 16);
            s += __shfl_xor(s, 8, 16);
            if (s < d1 || (s == d1 && m < i1)) { d2 = d1; i2 = i1; d1 = s; i1 = m; }
            else if (s < d2) { d2 = s; i2 = m; }
        }
    }
    if (!safe && lastgmin >= d1 - pbase + EPS_STOP) safe = true;  // post-check vs pv[5]

    if (j == 0) {
        idxws[n] = i1;
        out_idxf[n] = (float)i1;
        if (!safe) {
            int s = atomicAdd(rcntA, 1);
            if (s < RCAPA) rlistA[s] = n;
        } else if ((d2 - d1) < TAUF) {
            int s = atomicAdd(rcntB, 1);
            if (s < RCAP) { int4 v4 = make_int4(n, i1, i2, 0); ((int4*)rlistB)[s] = v4; }
        }
        lred[pl] = d1;
    }
    __syncthreads();
    if (t == 0) {
        float ls = 0.f;
        #pragma unroll
        for (int q = 0; q < 16; ++q) ls += lred[q];
        atomicAdd(losssum, ls);
    }
}

// ---------------- K4a: parallel full scan for !safe pixels ----------------
// 32 chunk-blocks per pixel, 256 codes/chunk; 16 lanes/code coalesced; fp64 accum.
__global__ __launch_bounds__(256) void k_scanp(
    const float* __restrict__ zws, const float* __restrict__ emb,
    const int* __restrict__ rcntA, const int* __restrict__ rlistA,
    double* __restrict__ scand, int* __restrict__ scani)
{
    int cnt = *rcntA; if (cnt > RCAPA) cnt = RCAPA;
    const int t = threadIdx.x;
    const int chunk = blockIdx.x & 31;
    const int gi = t >> 4, j = t & 15;
    __shared__ double sd[16];
    __shared__ int si[16];
    for (int e = blockIdx.x >> 5; e < cnt; e += 64) {
        const int n = rlistA[e];
        const float4 za = *(const float4*)&zws[(size_t)n * 128 + j * 8];
        const float4 zb = *(const float4*)&zws[(size_t)n * 128 + j * 8 + 4];
        double best = 1e300; int bi = 0x7fffffff;
        const int kbase = chunk * 256 + gi * 16;
        for (int c = 0; c < 16; ++c) {
            const int m = kbase + c;
            const float4 ea = *(const float4*)&emb[(size_t)m * 128 + j * 8];
            const float4 eb = *(const float4*)&emb[(size_t)m * 128 + j * 8 + 4];
            double s = 0.0, d;
            d = (double)za.x - (double)ea.x; s += d * d;
            d = (double)za.y - (double)ea.y; s += d * d;
            d = (double)za.z - (double)ea.z; s += d * d;
            d = (double)za.w - (double)ea.w; s += d * d;
            d = (double)zb.x - (double)eb.x; s += d * d;
            d = (double)zb.y - (double)eb.y; s += d * d;
            d = (double)zb.z - (double)eb.z; s += d * d;
            d = (double)zb.w - (double)eb.w; s += d * d;
            s += __shfl_xor(s, 1, 16);
            s += __shfl_xor(s, 2, 16);
            s += __shfl_xor(s, 4, 16);
            s += __shfl_xor(s, 8, 16);
            if (s < best) { best = s; bi = m; }   // m strictly increasing -> first-index
        }
        __syncthreads();
        if (j == 0) { sd[gi] = best; si[gi] = bi; }
        __syncthreads();
        if (t == 0) {
            double b = sd[0]; int ib = si[0];
            #pragma unroll
            for (int q = 1; q < 16; ++q)
                if (sd[q] < b || (sd[q] == b && si[q] < ib)) { b = sd[q]; ib = si[q]; }
            scand[e * 32 + chunk] = b;
            scani[e * 32 + chunk] = ib;
        }
    }
}

// ---------------- K4bc: fused finalize — blocks [0,32) merge chunk results (!safe),
// blocks [32,288) fp64 pair arbitration (near-tie). Pixel sets disjoint by construction.
__global__ __launch_bounds__(128) void k_fix(
    const float* __restrict__ x, const float* __restrict__ Wl, const float* __restrict__ bl,
    const float* __restrict__ emb,
    const int* __restrict__ rcntA, const int* __restrict__ rlistA,
    const double* __restrict__ scand, const int* __restrict__ scani,
    const int* __restrict__ rcntB, const int* __restrict__ rlistB,
    int* __restrict__ idxws, float* __restrict__ out_idxf)
{
    const int t = threadIdx.x;
    if (blockIdx.x < 32) {
        // ---- mergeA: 32 blocks, first wave only ----
        if (t < 64) {
            int cnt = *rcntA; if (cnt > RCAPA) cnt = RCAPA;
            for (int e = blockIdx.x; e < cnt; e += 32) {
                double b = 1e300; int ib = 0x7fffffff;
                if (t < 32) { b = scand[e * 32 + t]; ib = scani[e * 32 + t]; }
                #pragma unroll
                for (int o = 16; o; o >>= 1) {
                    double ob = __shfl_down(b, o, 64);
                    int oi = __shfl_down(ib, o, 64);
                    if (ob < b || (ob == b && oi < ib)) { b = ob; ib = oi; }
                }
                if (t == 0) { int n = rlistA[e]; idxws[n] = ib; out_idxf[n] = (float)ib; }
            }
        }
        return;
    }
    // ---- pairB: 256 blocks ----
    __shared__ double xs[128];
    __shared__ double red[128];
    int cnt = *rcntB; if (cnt > RCAP) cnt = RCAP;
    for (int e = (int)blockIdx.x - 32; e < cnt; e += 256) {
        const int4 v = ((const int4*)rlistB)[e];
        const int n = v.x, c1 = v.y, c2 = v.z;
        const int b = n >> 10, hw = n & 1023;
        __syncthreads();
        xs[t] = (double)x[(size_t)(b * 128 + t) * 1024 + hw];
        __syncthreads();
        double z = (double)bl[t];
        for (int c = 0; c < 128; ++c) z = fma((double)Wl[(size_t)t * 128 + c], xs[c], z);
        double d1v, d2v;
        double da = z - (double)emb[(size_t)c1 * 128 + t];
        red[t] = da * da; __syncthreads();
        for (int o = 64; o; o >>= 1) { if (t < o) red[t] += red[t + o]; __syncthreads(); }
        d1v = red[0]; __syncthreads();
        double db = z - (double)emb[(size_t)c2 * 128 + t];
        red[t] = db * db; __syncthreads();
        for (int o = 64; o; o >>= 1) { if (t < o) red[t] += red[t + o]; __syncthreads(); }
        d2v = red[0];
        if (t == 0) {
            int win = (d2v < d1v || (d2v == d1v && c2 < c1)) ? c2 : c1;
            idxws[n] = win;
            out_idxf[n] = (float)win;
        }
        __syncthreads();
    }
}

// ---------------- K5: gather + transpose + histogram (nontemporal out) ----------------
__global__ __launch_bounds__(256) void k_out(
    const float* __restrict__ emb, const int* __restrict__ idxws,
    float* __restrict__ outp /* d_out + 1 */, float* __restrict__ counts)
{
    const int t = threadIdx.x;
    const int b = blockIdx.x >> 2, h0 = (blockIdx.x & 3) << 3;
    const int n = b * 1024 + h0 * 32 + t;
    const int id = idxws[n];
    atomicAdd(&counts[id], 1.0f);
    const float4* ep = (const float4*)&emb[(size_t)id * 128];
    float* ob = outp + (size_t)b * 131072 + h0 * 32 + t;
    #pragma unroll 4
    for (int c4 = 0; c4 < 32; ++c4) {
        float4 v = ep[c4];
        __builtin_nontemporal_store(v.x, &ob[(c4 * 4 + 0) * 1024]);
        __builtin_nontemporal_store(v.y, &ob[(c4 * 4 + 1) * 1024]);
        __builtin_nontemporal_store(v.z, &ob[(c4 * 4 + 2) * 1024]);
        __builtin_nontemporal_store(v.w, &ob[(c4 * 4 + 3) * 1024]);
    }
}

// ---------------- K6: finalize loss + perplexity ----------------
__global__ __launch_bounds__(256) void k_final(
    const float* __restrict__ counts, const float* __restrict__ losssum, float* __restrict__ d_out)
{
    const int t = threadIdx.x;
    float ent = 0.f;
    for (int k = t; k < KCB; k += 256) {
        float p = counts[k] * (1.0f / 32768.0f);
        ent -= p * logf(p + 1e-10f);
    }
    #pragma unroll
    for (int o = 32; o; o >>= 1) ent += __shfl_down(ent, o, 64);
    __shared__ float wred[4];
    if ((t & 63) == 0) wred[t >> 6] = ent;
    __syncthreads();
    if (t == 0) {
        float e = wred[0] + wred[1] + wred[2] + wred[3];
        d_out[0] = 1.25f * (*losssum) * (1.0f / 4194304.0f);
        d_out[OUT_OFF_PERP] = expf(e);
    }
}

extern "C" void kernel_launch(void* const* d_in, const int* in_sizes, int n_in,
                              void* d_out, int out_size, void* d_ws, size_t ws_size,
                              hipStream_t stream) {
    (void)in_sizes; (void)n_in; (void)out_size; (void)ws_size;
    const float* x   = (const float*)d_in[0];
    const float* Wl  = (const float*)d_in[1];
    const float* bl  = (const float*)d_in[2];
    const float* emb = (const float*)d_in[3];
    float* out = (float*)d_out;
    char*  ws  = (char*)d_ws;

    _Float16* embFh = (_Float16*)(ws + WS_EMBFH);
    float* e2      = (float*)(ws + WS_E2);
    float* zws     = (float*)(ws + WS_ZWS);
    float4* cand   = (float4*)(ws + WS_CAND);
    int*   idxws   = (int*)  (ws + WS_IDX);
    int*   rlistA  = (int*)  (ws + WS_RLISTA);
    int*   rlistB  = (int*)  (ws + WS_RLISTB);
    double* scand  = (double*)(ws + WS_SCAND);
    int*   scani   = (int*)  (ws + WS_SCANI);
    float* counts  = (float*)(ws + WS_COUNTS);
    float* losssum = (float*)(ws + WS_LOSS);
    int*   rcntA   = (int*)  (ws + WS_RCNTA);
    int*   rcntB   = (int*)  (ws + WS_RCNTB);

    hipMemsetAsync(ws + WS_ZERO_OFF, 0, WS_ZERO_LEN, stream);

    k_e2<<<KCB / 4, 256, 0, stream>>>(emb, e2);
    k_prep<<<576, 256, 0, stream>>>(emb, e2, embFh);
    k_main<<<NPIX / 64, 256, 0, stream>>>(x, Wl, bl, embFh, zws, cand);
    k_rec<<<NPIX / 16, 256, 0, stream>>>(zws, emb, cand, idxws, out + OUT_OFF_IDX,
                                         losssum, rlistA, rcntA, rlistB, rcntB);
    k_scanp<<<2048, 256, 0, stream>>>(zws, emb, rcntA, rlistA, scand, scani);
    k_fix<<<288, 128, 0, stream>>>(x, Wl, bl, emb, rcntA, rlistA, scand, scani,
                                   rcntB, rlistB, idxws, out + OUT_OFF_IDX);
    k_out<<<128, 256, 0, stream>>>(emb, idxws, out + OUT_OFF_OUT, counts);
    k_final<<<1, 256, 0, stream>>>(counts, losssum, out);
}

// Round 7
// 277.157 us; speedup vs baseline: 1.1848x; 1.0712x over previous
//
#include <hip/hip_runtime.h>
#include <hip/hip_bf16.h>
#include <float.h>

// Problem constants
#define NPIX   32768      // B*H*W
#define CDIM   128
#define KCB    8192
#define EPS_STOP 0.30f    // mask quant (0.031) + f16-dot error bound
#define TAUF   0.012f     // exact fp32 gap guard -> fp64 arbitration
#define RCAP   8192
#define RCAPA  2048

typedef _Float16 f16x8 __attribute__((ext_vector_type(8)));
typedef float    f32x16 __attribute__((ext_vector_type(16)));

// ws layout (bytes)
#define WS_EMBFH   0           // 2,359,296
#define WS_E2      2359296     // 32,768
#define WS_ZWS     2392064     // 16,777,216
#define WS_CAND    19169280    // 1,048,576
#define WS_IDX     20217856    // 131,072
#define WS_RLISTA  20348928    // 32,768 (cap 2048 used)
#define WS_RLISTB  20381696    // 131,072 (8192 * int4)
#define WS_SCAND   20512768    // 524,288 (2048*32 double)
#define WS_SCANI   21037056    // 262,144 (2048*32 int)
#define WS_COUNTS  21299200    // 32,768
#define WS_LOSS    21331968    // 4
#define WS_RCNTA   21331972    // 4
#define WS_RCNTB   21331976    // 4
#define WS_ZERO_OFF 21299200
#define WS_ZERO_LEN 32780

// d_out layout (f32): [0]=loss, [1..4194304]=out BCHW, [4194305]=perplexity, [4194306..]=idx
#define OUT_OFF_OUT  1
#define OUT_OFF_PERP 4194305
#define OUT_OFF_IDX  4194306

__device__ __forceinline__ float min3f(float a, float b, float c) {
    return fminf(fminf(a, b), c);   // -> v_min3_f32
}

__device__ __forceinline__ void ins6(float f, float v[6]) {
    float a = fmaxf(v[0], f); v[0] = fminf(v[0], f);
    float b = fmaxf(v[1], a); v[1] = fminf(v[1], a);
    a = fmaxf(v[2], b); v[2] = fminf(v[2], b);
    b = fmaxf(v[3], a); v[3] = fminf(v[3], a);
    a = fmaxf(v[4], b); v[4] = fminf(v[4], b);
    v[5] = fminf(v[5], a);
}

__device__ __forceinline__ float packmin(float m, uint32_t id) {
    return __uint_as_float((__float_as_uint(m) & 0xFFFFFE00u) | id);
}

// ---------------- K0: e2[k] = sum_c emb[k][c]^2 ----------------
__global__ __launch_bounds__(256) void k_e2(const float* __restrict__ emb, float* __restrict__ e2) {
    int t = threadIdx.x;
    int wv = t >> 6, l = t & 63;
    int k = blockIdx.x * 4 + wv;
    const float2 v = *(const float2*)&emb[(size_t)k * 128 + l * 2];
    float s = v.x * v.x + v.y * v.y;
    #pragma unroll
    for (int o = 32; o; o >>= 1) s += __shfl_down(s, o, 64);
    if (l == 0) e2[k] = s;
}

// ---------------- K1: fragment-ordered -2*emb (f16), e2+512 hi/lo fold in step 8 ----------------
__global__ __launch_bounds__(256) void k_prep(const float* __restrict__ emb, const float* __restrict__ e2,
                                              _Float16* __restrict__ embFh) {
    int tid = blockIdx.x * 256 + threadIdx.x;   // < 147456 = 8192*18
    int m = tid / 18, r = tid % 18;
    int s = r >> 1, h = r & 1;
    f16x8 hv;
    #pragma unroll
    for (int j = 0; j < 8; ++j) hv[j] = (_Float16)0.0f;
    if (s < 8) {
        int c0 = s * 16 + h * 8;
        const float4 a = *(const float4*)&emb[(size_t)m * 128 + c0];
        const float4 b = *(const float4*)&emb[(size_t)m * 128 + c0 + 4];
        float vals[8] = {a.x, a.y, a.z, a.w, b.x, b.y, b.z, b.w};
        #pragma unroll
        for (int j = 0; j < 8; ++j) hv[j] = (_Float16)(-2.0f * vals[j]);
    } else if (h == 0) {
        float v = e2[m] + 512.0f;    // offset keeps packed values > 0 (z2 dropped)
        _Float16 eh = (_Float16)v;
        hv[0] = eh;                  // x B8[0]=1
        hv[1] = (_Float16)(v - (float)eh);   // x B8[1]=1
    }
    size_t base = (((size_t)(m >> 5) * 9 + s) * 64 + (m & 31) + h * 32) * 8;
    *(f16x8*)&embFh[base] = hv;
}

// ---------------- K2: fused linear + MFMA + packed group-min top-6 ----------------
// r3 structure (proven best, setprio removed): software-pipelined reduction — each
// tile's tail (tree16+ins6) is deferred until AFTER the next tile's 18-MFMA burst
// has issued. Ping-pong acc sets (e0/e1 vs o0/o1), named regs only.
__global__ __launch_bounds__(256, 2) void k_main(
    const float* __restrict__ x, const float* __restrict__ Wl, const float* __restrict__ bl,
    const _Float16* __restrict__ embFh,
    float* __restrict__ zws, float4* __restrict__ cand)
{
    __shared__ __align__(16) float As[64 * 132];   // z [p][c], pitch 132
    __shared__ __align__(16) float Xs[64 * 66];    // x staging / merge scratch
    __shared__ float z2p[256];                      // z^2 partials [p][ig]

    const int t  = threadIdx.x;
    const int n0 = blockIdx.x * 64;
    const int b  = n0 >> 10;
    const int hw0 = n0 & 1023;

    // ===== Phase 1: z for 64 pixels =====
    {
        const int p = t & 63, ig = t >> 6;
        float accz[32];
        const float4* bl4 = (const float4*)(bl + ig * 32);
        #pragma unroll
        for (int q = 0; q < 8; ++q) {
            float4 v = bl4[q];
            accz[4*q+0] = v.x; accz[4*q+1] = v.y; accz[4*q+2] = v.z; accz[4*q+3] = v.w;
        }
        for (int hf = 0; hf < 2; ++hf) {
            __syncthreads();
            for (int r = 0; r < 16; ++r) {
                int lin = r * 256 + t;
                int cc = lin >> 6, pp = lin & 63;
                Xs[cc * 66 + pp] = x[(size_t)(b * 128 + hf * 64 + cc) * 1024 + hw0 + pp];
            }
            __syncthreads();
            for (int cc4 = 0; cc4 < 16; ++cc4) {
                float xv0 = Xs[(cc4*4+0) * 66 + p];
                float xv1 = Xs[(cc4*4+1) * 66 + p];
                float xv2 = Xs[(cc4*4+2) * 66 + p];
                float xv3 = Xs[(cc4*4+3) * 66 + p];
                #pragma unroll
                for (int ii = 0; ii < 32; ++ii) {
                    const float4 w4 = *(const float4*)&Wl[(size_t)(ig*32+ii) * 128 + hf*64 + cc4*4];
                    float a = accz[ii];
                    a = fmaf(w4.x, xv0, a);
                    a = fmaf(w4.y, xv1, a);
                    a = fmaf(w4.z, xv2, a);
                    a = fmaf(w4.w, xv3, a);
                    accz[ii] = a;
                }
            }
        }
        float ssq = 0.f;
        float4* ao = (float4*)&As[p * 132 + ig * 32];
        float4* zo = (float4*)(zws + (size_t)(n0 + p) * 128 + ig * 32);
        #pragma unroll
        for (int q = 0; q < 8; ++q) {
            float4 v = make_float4(accz[4*q+0], accz[4*q+1], accz[4*q+2], accz[4*q+3]);
            ao[q] = v;
            zo[q] = v;
            ssq = fmaf(v.x, v.x, fmaf(v.y, v.y, fmaf(v.z, v.z, fmaf(v.w, v.w, ssq))));
        }
        z2p[p * 4 + ig] = ssq;
    }
    __syncthreads();

    // ===== Phase 2: B fragments (z f16) + constant fold step =====
    const int l = t & 63, w = t >> 6;
    const int half = l >> 5, pcol = l & 31;
    f16x8 B0[9], B1[9];
    #pragma unroll
    for (int nt = 0; nt < 2; ++nt) {
        int p = nt * 32 + pcol;
        #pragma unroll
        for (int s = 0; s < 8; ++s) {
            const float* zp = &As[p * 132 + s * 16 + half * 8];
            float4 v0 = *(const float4*)zp;
            float4 v1 = *(const float4*)(zp + 4);
            float vals[8] = {v0.x, v0.y, v0.z, v0.w, v1.x, v1.y, v1.z, v1.w};
            f16x8 hh;
            #pragma unroll
            for (int j2 = 0; j2 < 8; ++j2) hh[j2] = (_Float16)vals[j2];
            if (nt == 0) B0[s] = hh; else B1[s] = hh;
        }
    }
    {
        f16x8 b8;
        #pragma unroll
        for (int j2 = 0; j2 < 8; ++j2) b8[j2] = (_Float16)0.0f;
        if (half == 0) { b8[0] = (_Float16)1.0f; b8[1] = (_Float16)1.0f; }
        B0[8] = b8; B1[8] = b8;
    }

    // ===== Phase 3: K-loop, deferred-tail pipeline =====
    auto tree16 = [](const f32x16& v) -> float {
        float a = min3f(v[0], v[1], v[2]);
        float bb = min3f(v[3], v[4], v[5]);
        float c = min3f(v[6], v[7], v[8]);
        float d = min3f(v[9], v[10], v[11]);
        float e = min3f(v[12], v[13], v[14]);
        float f = min3f(a, bb, c);
        float g = min3f(d, e, v[15]);
        return fminf(f, g);
    };

    float gv[6] = {3e38f, 3e38f, 3e38f, 3e38f, 3e38f, 3e38f};   // tile0: px = pcol
    float hv[6] = {3e38f, 3e38f, 3e38f, 3e38f, 3e38f, 3e38f};   // tile1: px = 32+pcol
    const f16x8* Ahp = (const f16x8*)embFh;
    f16x8 aE[9], aO[9];
    {
        const f16x8* P = Ahp + (size_t)w * 576 + l;
        #pragma unroll
        for (int s = 0; s < 9; ++s) aE[s] = P[s * 64];
    }
    {
        const f16x8* P = Ahp + (size_t)(w + 4) * 576 + l;
        #pragma unroll
        for (int s = 0; s < 9; ++s) aO[s] = P[s * 64];
    }

    f32x16 e0, e1, o0, o1;
    uint32_t idv = (uint32_t)((w << 1) | half);

    // prologue: burst even tile w
    e0 = {}; e1 = {};
    #pragma unroll
    for (int s = 0; s < 9; ++s) {
        e0 = __builtin_amdgcn_mfma_f32_32x32x16_f16(aE[s], B0[s], e0, 0, 0, 0);
        e1 = __builtin_amdgcn_mfma_f32_32x32x16_f16(aE[s], B1[s], e1, 0, 0, 0);
    }

    for (int it = 0; it < 31; ++it) {
        const int g = w + it * 8;
        {   // refill aE <- tile g+8 (consumed by burstE at end of this iteration)
            const f16x8* P = Ahp + (size_t)(g + 8) * 576 + l;
            #pragma unroll
            for (int s = 0; s < 9; ++s) aE[s] = P[s * 64];
        }
        // burst odd tile g+4
        o0 = {}; o1 = {};
        #pragma unroll
        for (int s = 0; s < 9; ++s) {
            o0 = __builtin_amdgcn_mfma_f32_32x32x16_f16(aO[s], B0[s], o0, 0, 0, 0);
            o1 = __builtin_amdgcn_mfma_f32_32x32x16_f16(aO[s], B1[s], o1, 0, 0, 0);
        }
        // deferred tail: even tile g (burst issued one burst ago)
        {
            float m0 = tree16(e0), m1 = tree16(e1);
            ins6(packmin(m0, idv), gv);
            ins6(packmin(m1, idv), hv);
        }
        {   // refill aO <- tile g+12 (consumed by burstO next iteration / epilogue)
            const f16x8* P = Ahp + (size_t)(g + 12) * 576 + l;
            #pragma unroll
            for (int s = 0; s < 9; ++s) aO[s] = P[s * 64];
        }
        // burst even tile g+8
        e0 = {}; e1 = {};
        #pragma unroll
        for (int s = 0; s < 9; ++s) {
            e0 = __builtin_amdgcn_mfma_f32_32x32x16_f16(aE[s], B0[s], e0, 0, 0, 0);
            e1 = __builtin_amdgcn_mfma_f32_32x32x16_f16(aE[s], B1[s], e1, 0, 0, 0);
        }
        // deferred tail: odd tile g+4
        {
            float m0 = tree16(o0), m1 = tree16(o1);
            ins6(packmin(m0, idv + 8u), gv);
            ins6(packmin(m1, idv + 8u), hv);
        }
        idv += 16u;
    }
    // epilogue: last odd tile w+252 (aO loaded at it=30), then both remaining tails
    o0 = {}; o1 = {};
    #pragma unroll
    for (int s = 0; s < 9; ++s) {
        o0 = __builtin_amdgcn_mfma_f32_32x32x16_f16(aO[s], B0[s], o0, 0, 0, 0);
        o1 = __builtin_amdgcn_mfma_f32_32x32x16_f16(aO[s], B1[s], o1, 0, 0, 0);
    }
    {   // tail even tile w+248
        float m0 = tree16(e0), m1 = tree16(e1);
        ins6(packmin(m0, idv), gv);
        ins6(packmin(m1, idv), hv);
    }
    {   // tail odd tile w+252
        float m0 = tree16(o0), m1 = tree16(o1);
        ins6(packmin(m0, idv + 8u), gv);
        ins6(packmin(m1, idv + 8u), hv);
    }

    // ===== Phase 4: cross-wave merge per pixel, write cand (6 groups + z2) =====
    __syncthreads();
    float* Ms = Xs;   // [64 px][8 slots][6]
    const int slot = (w << 1) | half;
    #pragma unroll
    for (int q = 0; q < 6; ++q) {
        Ms[(pcol * 8 + slot) * 6 + q] = gv[q];
        Ms[((32 + pcol) * 8 + slot) * 6 + q] = hv[q];
    }
    __syncthreads();
    if (t < 64) {
        float v6[6] = {3e38f, 3e38f, 3e38f, 3e38f, 3e38f, 3e38f};
        #pragma unroll
        for (int s = 0; s < 48; ++s) ins6(Ms[t * 48 + s], v6);
        float z2 = z2p[t*4+0] + z2p[t*4+1] + z2p[t*4+2] + z2p[t*4+3];
        cand[(size_t)(n0 + t) * 2 + 0] = make_float4(v6[0], v6[1], v6[2], v6[3]);
        cand[(size_t)(n0 + t) * 2 + 1] = make_float4(v6[4], v6[5], z2, 0.f);
    }
}

// ---------------- K3: early-exit exact fp32 over candidate groups ----------------
// Packed id decode: id = bits[8:0], tile = id>>1, half = id&1;
// group codes m = tile*32 + half*4 + {(c&3) + 8*(c>>2)}.
// Flags: !safe -> rlistA (parallel full scan); near-tie -> rlistB (fp64 pair arb).
__global__ __launch_bounds__(256) void k_rec(
    const float* __restrict__ zws, const float* __restrict__ emb,
    const float4* __restrict__ cand, int* __restrict__ idxws,
    float* __restrict__ out_idxf, float* __restrict__ losssum,
    int* __restrict__ rlistA, int* __restrict__ rcntA,
    int* __restrict__ rlistB, int* __restrict__ rcntB)
{
    __shared__ float lred[16];
    const int t = threadIdx.x;
    const int pl = t >> 4, j = t & 15;
    const int n = blockIdx.x * 16 + pl;

    const float4 za = *(const float4*)&zws[(size_t)n * 128 + j * 8];
    const float4 zb = *(const float4*)&zws[(size_t)n * 128 + j * 8 + 4];
    const float4 c0 = cand[(size_t)n * 2 + 0];
    const float4 c1 = cand[(size_t)n * 2 + 1];
    const float pv[6] = {c0.x, c0.y, c0.z, c0.w, c1.x, c1.y};
    const float pbase = c1.z - 512.0f;   // d = packed + pbase

    float d1 = 3e38f, d2 = 3e38f; int i1 = 0x7fffffff, i2 = 0x7fffffff;
    bool safe = false;
    float lastgmin = 0.f;
    for (int q = 0; q < 6; ++q) {
        uint32_t bits = __float_as_uint(pv[q]);
        float gmin = __uint_as_float(bits & 0xFFFFFE00u);
        lastgmin = gmin;
        if (gmin >= d1 - pbase + EPS_STOP) { safe = true; break; }
        const int mbase = (int)((bits >> 1) & 255u) * 32 + (int)((bits & 1u) << 2); // tile*32 + half*4
        #pragma unroll
        for (int c = 0; c < 16; ++c) {
            int m = mbase + (c & 3) + 8 * (c >> 2);
            const float4 ea = *(const float4*)&emb[(size_t)m * 128 + j * 8];
            const float4 eb = *(const float4*)&emb[(size_t)m * 128 + j * 8 + 4];
            float da0 = za.x - ea.x, da1 = za.y - ea.y, da2 = za.z - ea.z, da3 = za.w - ea.w;
            float db0 = zb.x - eb.x, db1 = zb.y - eb.y, db2 = zb.z - eb.z, db3 = zb.w - eb.w;
            float s = da0*da0; s = fmaf(da1, da1, s); s = fmaf(da2, da2, s); s = fmaf(da3, da3, s);
            s = fmaf(db0, db0, s); s = fmaf(db1, db1, s); s = fmaf(db2, db2, s); s = fmaf(db3, db3, s);
            s += __shfl_xor(s, 1, 16);
            s += __shfl_xor(s, 2, 16);
            s += __shfl_xor(s, 4, 16);
            s += __shfl_xor(s, 8, 16);
            if (s < d1 || (s == d1 && m < i1)) { d2 = d1; i2 = i1; d1 = s; i1 = m; }
            else if (s < d2) { d2 = s; i2 = m; }
        }
    }
    if (!safe && lastgmin >= d1 - pbase + EPS_STOP) safe = true;  // post-check vs pv[5]

    if (j == 0) {
        idxws[n] = i1;
        out_idxf[n] = (float)i1;
        if (!safe) {
            int s = atomicAdd(rcntA, 1);
            if (s < RCAPA) rlistA[s] = n;
        } else if ((d2 - d1) < TAUF) {
            int s = atomicAdd(rcntB, 1);
            if (s < RCAP) { int4 v4 = make_int4(n, i1, i2, 0); ((int4*)rlistB)[s] = v4; }
        }
        lred[pl] = d1;
    }
    __syncthreads();
    if (t == 0) {
        float ls = 0.f;
        #pragma unroll
        for (int q = 0; q < 16; ++q) ls += lred[q];
        atomicAdd(losssum, ls);
    }
}

// ---------------- K4a: parallel full scan for !safe pixels ----------------
// 32 chunk-blocks per pixel, 256 codes/chunk; 16 lanes/code coalesced; fp64 accum.
__global__ __launch_bounds__(256) void k_scanp(
    const float* __restrict__ zws, const float* __restrict__ emb,
    const int* __restrict__ rcntA, const int* __restrict__ rlistA,
    double* __restrict__ scand, int* __restrict__ scani)
{
    int cnt = *rcntA; if (cnt > RCAPA) cnt = RCAPA;
    const int t = threadIdx.x;
    const int chunk = blockIdx.x & 31;
    const int gi = t >> 4, j = t & 15;
    __shared__ double sd[16];
    __shared__ int si[16];
    for (int e = blockIdx.x >> 5; e < cnt; e += 64) {
        const int n = rlistA[e];
        const float4 za = *(const float4*)&zws[(size_t)n * 128 + j * 8];
        const float4 zb = *(const float4*)&zws[(size_t)n * 128 + j * 8 + 4];
        double best = 1e300; int bi = 0x7fffffff;
        const int kbase = chunk * 256 + gi * 16;
        for (int c = 0; c < 16; ++c) {
            const int m = kbase + c;
            const float4 ea = *(const float4*)&emb[(size_t)m * 128 + j * 8];
            const float4 eb = *(const float4*)&emb[(size_t)m * 128 + j * 8 + 4];
            double s = 0.0, d;
            d = (double)za.x - (double)ea.x; s += d * d;
            d = (double)za.y - (double)ea.y; s += d * d;
            d = (double)za.z - (double)ea.z; s += d * d;
            d = (double)za.w - (double)ea.w; s += d * d;
            d = (double)zb.x - (double)eb.x; s += d * d;
            d = (double)zb.y - (double)eb.y; s += d * d;
            d = (double)zb.z - (double)eb.z; s += d * d;
            d = (double)zb.w - (double)eb.w; s += d * d;
            s += __shfl_xor(s, 1, 16);
            s += __shfl_xor(s, 2, 16);
            s += __shfl_xor(s, 4, 16);
            s += __shfl_xor(s, 8, 16);
            if (s < best) { best = s; bi = m; }   // m strictly increasing -> first-index
        }
        __syncthreads();
        if (j == 0) { sd[gi] = best; si[gi] = bi; }
        __syncthreads();
        if (t == 0) {
            double b = sd[0]; int ib = si[0];
            #pragma unroll
            for (int q = 1; q < 16; ++q)
                if (sd[q] < b || (sd[q] == b && si[q] < ib)) { b = sd[q]; ib = si[q]; }
            scand[e * 32 + chunk] = b;
            scani[e * 32 + chunk] = ib;
        }
    }
}

// ---------------- K4bc: fused finalize — blocks [0,32) merge chunk results (!safe),
// blocks [32,288) fp64 pair arbitration (near-tie). Pixel sets disjoint by construction.
__global__ __launch_bounds__(128) void k_fix(
    const float* __restrict__ x, const float* __restrict__ Wl, const float* __restrict__ bl,
    const float* __restrict__ emb,
    const int* __restrict__ rcntA, const int* __restrict__ rlistA,
    const double* __restrict__ scand, const int* __restrict__ scani,
    const int* __restrict__ rcntB, const int* __restrict__ rlistB,
    int* __restrict__ idxws, float* __restrict__ out_idxf)
{
    const int t = threadIdx.x;
    if (blockIdx.x < 32) {
        // ---- mergeA: 32 blocks, first wave only ----
        if (t < 64) {
            int cnt = *rcntA; if (cnt > RCAPA) cnt = RCAPA;
            for (int e = blockIdx.x; e < cnt; e += 32) {
                double b = 1e300; int ib = 0x7fffffff;
                if (t < 32) { b = scand[e * 32 + t]; ib = scani[e * 32 + t]; }
                #pragma unroll
                for (int o = 16; o; o >>= 1) {
                    double ob = __shfl_down(b, o, 64);
                    int oi = __shfl_down(ib, o, 64);
                    if (ob < b || (ob == b && oi < ib)) { b = ob; ib = oi; }
                }
                if (t == 0) { int n = rlistA[e]; idxws[n] = ib; out_idxf[n] = (float)ib; }
            }
        }
        return;
    }
    // ---- pairB: 256 blocks ----
    __shared__ double xs[128];
    __shared__ double red[128];
    int cnt = *rcntB; if (cnt > RCAP) cnt = RCAP;
    for (int e = (int)blockIdx.x - 32; e < cnt; e += 256) {
        const int4 v = ((const int4*)rlistB)[e];
        const int n = v.x, c1 = v.y, c2 = v.z;
        const int b = n >> 10, hw = n & 1023;
        __syncthreads();
        xs[t] = (double)x[(size_t)(b * 128 + t) * 1024 + hw];
        __syncthreads();
        double z = (double)bl[t];
        for (int c = 0; c < 128; ++c) z = fma((double)Wl[(size_t)t * 128 + c], xs[c], z);
        double d1v, d2v;
        double da = z - (double)emb[(size_t)c1 * 128 + t];
        red[t] = da * da; __syncthreads();
        for (int o = 64; o; o >>= 1) { if (t < o) red[t] += red[t + o]; __syncthreads(); }
        d1v = red[0]; __syncthreads();
        double db = z - (double)emb[(size_t)c2 * 128 + t];
        red[t] = db * db; __syncthreads();
        for (int o = 64; o; o >>= 1) { if (t < o) red[t] += red[t + o]; __syncthreads(); }
        d2v = red[0];
        if (t == 0) {
            int win = (d2v < d1v || (d2v == d1v && c2 < c1)) ? c2 : c1;
            idxws[n] = win;
            out_idxf[n] = (float)win;
        }
        __syncthreads();
    }
}

// ---------------- K5: gather + transpose + histogram ----------------
// 512 blocks x 256 thr (4x occupancy of old 128-block version): each block covers
// 64 pixels (2 h-rows); each WAVE owns one channel-quarter -> 8 gather loads/thread
// (was 32) and fully coalesced 64-lane stores per channel row.
__global__ __launch_bounds__(256) void k_out(
    const float* __restrict__ emb, const int* __restrict__ idxws,
    float* __restrict__ outp /* d_out + 1 */, float* __restrict__ counts)
{
    const int t = threadIdx.x;
    const int b  = blockIdx.x >> 4;          // 32 batches
    const int h2 = blockIdx.x & 15;          // 16 groups of 64 pixels
    const int pix = t & 63;
    const int cq  = t >> 6;                  // channel quarter (one per wave)
    const int n = b * 1024 + h2 * 64 + pix;
    const int id = idxws[n];
    if (cq == 0) atomicAdd(&counts[id], 1.0f);
    const float4* ep = (const float4*)&emb[(size_t)id * 128 + cq * 32];
    float* ob = outp + (size_t)b * 131072 + (size_t)cq * 32768 + h2 * 64 + pix;
    #pragma unroll
    for (int c4 = 0; c4 < 8; ++c4) {
        float4 v = ep[c4];
        __builtin_nontemporal_store(v.x, &ob[(c4 * 4 + 0) * 1024]);
        __builtin_nontemporal_store(v.y, &ob[(c4 * 4 + 1) * 1024]);
        __builtin_nontemporal_store(v.z, &ob[(c4 * 4 + 2) * 1024]);
        __builtin_nontemporal_store(v.w, &ob[(c4 * 4 + 3) * 1024]);
    }
}

// ---------------- K6: finalize loss + perplexity ----------------
__global__ __launch_bounds__(256) void k_final(
    const float* __restrict__ counts, const float* __restrict__ losssum, float* __restrict__ d_out)
{
    const int t = threadIdx.x;
    float ent = 0.f;
    for (int k = t; k < KCB; k += 256) {
        float p = counts[k] * (1.0f / 32768.0f);
        ent -= p * logf(p + 1e-10f);
    }
    #pragma unroll
    for (int o = 32; o; o >>= 1) ent += __shfl_down(ent, o, 64);
    __shared__ float wred[4];
    if ((t & 63) == 0) wred[t >> 6] = ent;
    __syncthreads();
    if (t == 0) {
        float e = wred[0] + wred[1] + wred[2] + wred[3];
        d_out[0] = 1.25f * (*losssum) * (1.0f / 4194304.0f);
        d_out[OUT_OFF_PERP] = expf(e);
    }
}

extern "C" void kernel_launch(void* const* d_in, const int* in_sizes, int n_in,
                              void* d_out, int out_size, void* d_ws, size_t ws_size,
                              hipStream_t stream) {
    (void)in_sizes; (void)n_in; (void)out_size; (void)ws_size;
    const float* x   = (const float*)d_in[0];
    const float* Wl  = (const float*)d_in[1];
    const float* bl  = (const float*)d_in[2];
    const float* emb = (const float*)d_in[3];
    float* out = (float*)d_out;
    char*  ws  = (char*)d_ws;

    _Float16* embFh = (_Float16*)(ws + WS_EMBFH);
    float* e2      = (float*)(ws + WS_E2);
    float* zws     = (float*)(ws + WS_ZWS);
    float4* cand   = (float4*)(ws + WS_CAND);
    int*   idxws   = (int*)  (ws + WS_IDX);
    int*   rlistA  = (int*)  (ws + WS_RLISTA);
    int*   rlistB  = (int*)  (ws + WS_RLISTB);
    double* scand  = (double*)(ws + WS_SCAND);
    int*   scani   = (int*)  (ws + WS_SCANI);
    float* counts  = (float*)(ws + WS_COUNTS);
    float* losssum = (float*)(ws + WS_LOSS);
    int*   rcntA   = (int*)  (ws + WS_RCNTA);
    int*   rcntB   = (int*)  (ws + WS_RCNTB);

    hipMemsetAsync(ws + WS_ZERO_OFF, 0, WS_ZERO_LEN, stream);

    k_e2<<<KCB / 4, 256, 0, stream>>>(emb, e2);
    k_prep<<<576, 256, 0, stream>>>(emb, e2, embFh);
    k_main<<<NPIX / 64, 256, 0, stream>>>(x, Wl, bl, embFh, zws, cand);
    k_rec<<<NPIX / 16, 256, 0, stream>>>(zws, emb, cand, idxws, out + OUT_OFF_IDX,
                                         losssum, rlistA, rcntA, rlistB, rcntB);
    k_scanp<<<2048, 256, 0, stream>>>(zws, emb, rcntA, rlistA, scand, scani);
    k_fix<<<288, 128, 0, stream>>>(x, Wl, bl, emb, rcntA, rlistA, scand, scani,
                                   rcntB, rlistB, idxws, out + OUT_OFF_IDX);
    k_out<<<512, 256, 0, stream>>>(emb, idxws, out + OUT_OFF_OUT, counts);
    k_final<<<1, 256, 0, stream>>>(counts, losssum, out);
}

// Round 8
// 275.640 us; speedup vs baseline: 1.1913x; 1.0055x over previous
//
#include <hip/hip_runtime.h>
#include <hip/hip_bf16.h>
#include <float.h>

// Problem constants
#define NPIX   32768      // B*H*W
#define CDIM   128
#define KCB    8192
#define EPS_STOP 0.30f    // mask quant (0.031) + f16-dot error bound
#define TAUF   0.012f     // exact fp32 gap guard -> fp64 arbitration
#define RCAP   8192
#define RCAPA  2048

typedef _Float16 f16x8 __attribute__((ext_vector_type(8)));
typedef float    f32x16 __attribute__((ext_vector_type(16)));

// ws layout (bytes)
#define WS_EMBFH   0           // 2,359,296
#define WS_E2      2359296     // 32,768 (unused now)
#define WS_ZWS     2392064     // 16,777,216
#define WS_CAND    19169280    // 1,048,576
#define WS_IDX     20217856    // 131,072
#define WS_RLISTA  20348928    // 32,768 (cap 2048 used)
#define WS_RLISTB  20381696    // 131,072 (8192 * int4)
#define WS_SCAND   20512768    // 524,288 (2048*32 double)
#define WS_SCANI   21037056    // 262,144 (2048*32 int)
#define WS_COUNTS  21299200    // 32,768
#define WS_LOSS    21331968    // 4
#define WS_RCNTA   21331972    // 4
#define WS_RCNTB   21331976    // 4
#define WS_ZERO_OFF 21299200
#define WS_ZERO_LEN 32780      // 8195 ints

// d_out layout (f32): [0]=loss, [1..4194304]=out BCHW, [4194305]=perplexity, [4194306..]=idx
#define OUT_OFF_OUT  1
#define OUT_OFF_PERP 4194305
#define OUT_OFF_IDX  4194306

__device__ __forceinline__ float min3f(float a, float b, float c) {
    return fminf(fminf(a, b), c);   // -> v_min3_f32
}

__device__ __forceinline__ void ins6(float f, float v[6]) {
    float a = fmaxf(v[0], f); v[0] = fminf(v[0], f);
    float b = fmaxf(v[1], a); v[1] = fminf(v[1], a);
    a = fmaxf(v[2], b); v[2] = fminf(v[2], b);
    b = fmaxf(v[3], a); v[3] = fminf(v[3], a);
    a = fmaxf(v[4], b); v[4] = fminf(v[4], b);
    v[5] = fminf(v[5], a);
}

__device__ __forceinline__ float packmin(float m, uint32_t id) {
    return __uint_as_float((__float_as_uint(m) & 0xFFFFFE00u) | id);
}

// ---------------- K01: fused e2 + fragment prep + workspace zeroing ----------------
// One wave per codebook row m: lane l loads ch {2l,2l+1} (coalesced), e2 via the
// SAME shfl_down reduce as the old k_e2 (bit-identical); row staged in LDS; lanes
// 0..17 emit the 18 f16x8 fragments (-2*emb, e2+512 hi/lo fold, zero pad).
// Blocks 0..8 additionally zero the counts/loss/rcnt region (replaces memset).
__global__ __launch_bounds__(256) void k_prep2(const float* __restrict__ emb,
                                               _Float16* __restrict__ embFh,
                                               int* __restrict__ zerobuf) {
    const int t = threadIdx.x, w = t >> 6, l = t & 63;
    if (blockIdx.x < 9) {
        int idx0 = blockIdx.x * 1024 + t * 4;
        #pragma unroll
        for (int k = 0; k < 4; ++k)
            if (idx0 + k < 8195) zerobuf[idx0 + k] = 0;
    }
    __shared__ float rs[4][128];
    const int m = blockIdx.x * 4 + w;
    const float2 v = *(const float2*)&emb[(size_t)m * 128 + l * 2];
    rs[w][l * 2] = v.x; rs[w][l * 2 + 1] = v.y;
    float s = v.x * v.x + v.y * v.y;
    #pragma unroll
    for (int o = 32; o; o >>= 1) s += __shfl_down(s, o, 64);
    const float e2v = __shfl(s, 0, 64);

    f16x8 hv;
    #pragma unroll
    for (int j = 0; j < 8; ++j) hv[j] = (_Float16)0.0f;
    if (l < 16) {
        const float* rp = &rs[w][l * 8];
        #pragma unroll
        for (int j = 0; j < 8; ++j) hv[j] = (_Float16)(-2.0f * rp[j]);
    } else if (l == 16) {
        float vv = e2v + 512.0f;
        _Float16 eh = (_Float16)vv;
        hv[0] = eh;
        hv[1] = (_Float16)(vv - (float)eh);
    }
    if (l < 18) {
        const int s_ = l >> 1, h_ = l & 1;   // l<16: ch base = l*8 matches rp
        size_t base = (((size_t)(m >> 5) * 9 + s_) * 64 + (m & 31) + h_ * 32) * 8;
        *(f16x8*)&embFh[base] = hv;
    }
}

// ---------------- K2: fused linear + MFMA + packed group-min top-6 ----------------
// r3 structure (proven best): software-pipelined reduction — each tile's tail
// (tree16+ins6) is deferred until AFTER the next tile's 18-MFMA burst has issued.
// Ping-pong acc sets (e0/e1 vs o0/o1), named regs only. UNCHANGED from R7.
__global__ __launch_bounds__(256, 2) void k_main(
    const float* __restrict__ x, const float* __restrict__ Wl, const float* __restrict__ bl,
    const _Float16* __restrict__ embFh,
    float* __restrict__ zws, float4* __restrict__ cand)
{
    __shared__ __align__(16) float As[64 * 132];   // z [p][c], pitch 132
    __shared__ __align__(16) float Xs[64 * 66];    // x staging / merge scratch
    __shared__ float z2p[256];                      // z^2 partials [p][ig]

    const int t  = threadIdx.x;
    const int n0 = blockIdx.x * 64;
    const int b  = n0 >> 10;
    const int hw0 = n0 & 1023;

    // ===== Phase 1: z for 64 pixels =====
    {
        const int p = t & 63, ig = t >> 6;
        float accz[32];
        const float4* bl4 = (const float4*)(bl + ig * 32);
        #pragma unroll
        for (int q = 0; q < 8; ++q) {
            float4 v = bl4[q];
            accz[4*q+0] = v.x; accz[4*q+1] = v.y; accz[4*q+2] = v.z; accz[4*q+3] = v.w;
        }
        for (int hf = 0; hf < 2; ++hf) {
            __syncthreads();
            for (int r = 0; r < 16; ++r) {
                int lin = r * 256 + t;
                int cc = lin >> 6, pp = lin & 63;
                Xs[cc * 66 + pp] = x[(size_t)(b * 128 + hf * 64 + cc) * 1024 + hw0 + pp];
            }
            __syncthreads();
            for (int cc4 = 0; cc4 < 16; ++cc4) {
                float xv0 = Xs[(cc4*4+0) * 66 + p];
                float xv1 = Xs[(cc4*4+1) * 66 + p];
                float xv2 = Xs[(cc4*4+2) * 66 + p];
                float xv3 = Xs[(cc4*4+3) * 66 + p];
                #pragma unroll
                for (int ii = 0; ii < 32; ++ii) {
                    const float4 w4 = *(const float4*)&Wl[(size_t)(ig*32+ii) * 128 + hf*64 + cc4*4];
                    float a = accz[ii];
                    a = fmaf(w4.x, xv0, a);
                    a = fmaf(w4.y, xv1, a);
                    a = fmaf(w4.z, xv2, a);
                    a = fmaf(w4.w, xv3, a);
                    accz[ii] = a;
                }
            }
        }
        float ssq = 0.f;
        float4* ao = (float4*)&As[p * 132 + ig * 32];
        float4* zo = (float4*)(zws + (size_t)(n0 + p) * 128 + ig * 32);
        #pragma unroll
        for (int q = 0; q < 8; ++q) {
            float4 v = make_float4(accz[4*q+0], accz[4*q+1], accz[4*q+2], accz[4*q+3]);
            ao[q] = v;
            zo[q] = v;
            ssq = fmaf(v.x, v.x, fmaf(v.y, v.y, fmaf(v.z, v.z, fmaf(v.w, v.w, ssq))));
        }
        z2p[p * 4 + ig] = ssq;
    }
    __syncthreads();

    // ===== Phase 2: B fragments (z f16) + constant fold step =====
    const int l = t & 63, w = t >> 6;
    const int half = l >> 5, pcol = l & 31;
    f16x8 B0[9], B1[9];
    #pragma unroll
    for (int nt = 0; nt < 2; ++nt) {
        int p = nt * 32 + pcol;
        #pragma unroll
        for (int s = 0; s < 8; ++s) {
            const float* zp = &As[p * 132 + s * 16 + half * 8];
            float4 v0 = *(const float4*)zp;
            float4 v1 = *(const float4*)(zp + 4);
            float vals[8] = {v0.x, v0.y, v0.z, v0.w, v1.x, v1.y, v1.z, v1.w};
            f16x8 hh;
            #pragma unroll
            for (int j2 = 0; j2 < 8; ++j2) hh[j2] = (_Float16)vals[j2];
            if (nt == 0) B0[s] = hh; else B1[s] = hh;
        }
    }
    {
        f16x8 b8;
        #pragma unroll
        for (int j2 = 0; j2 < 8; ++j2) b8[j2] = (_Float16)0.0f;
        if (half == 0) { b8[0] = (_Float16)1.0f; b8[1] = (_Float16)1.0f; }
        B0[8] = b8; B1[8] = b8;
    }

    // ===== Phase 3: K-loop, deferred-tail pipeline =====
    auto tree16 = [](const f32x16& v) -> float {
        float a = min3f(v[0], v[1], v[2]);
        float bb = min3f(v[3], v[4], v[5]);
        float c = min3f(v[6], v[7], v[8]);
        float d = min3f(v[9], v[10], v[11]);
        float e = min3f(v[12], v[13], v[14]);
        float f = min3f(a, bb, c);
        float g = min3f(d, e, v[15]);
        return fminf(f, g);
    };

    float gv[6] = {3e38f, 3e38f, 3e38f, 3e38f, 3e38f, 3e38f};   // tile0: px = pcol
    float hv[6] = {3e38f, 3e38f, 3e38f, 3e38f, 3e38f, 3e38f};   // tile1: px = 32+pcol
    const f16x8* Ahp = (const f16x8*)embFh;
    f16x8 aE[9], aO[9];
    {
        const f16x8* P = Ahp + (size_t)w * 576 + l;
        #pragma unroll
        for (int s = 0; s < 9; ++s) aE[s] = P[s * 64];
    }
    {
        const f16x8* P = Ahp + (size_t)(w + 4) * 576 + l;
        #pragma unroll
        for (int s = 0; s < 9; ++s) aO[s] = P[s * 64];
    }

    f32x16 e0, e1, o0, o1;
    uint32_t idv = (uint32_t)((w << 1) | half);

    // prologue: burst even tile w
    e0 = {}; e1 = {};
    #pragma unroll
    for (int s = 0; s < 9; ++s) {
        e0 = __builtin_amdgcn_mfma_f32_32x32x16_f16(aE[s], B0[s], e0, 0, 0, 0);
        e1 = __builtin_amdgcn_mfma_f32_32x32x16_f16(aE[s], B1[s], e1, 0, 0, 0);
    }

    for (int it = 0; it < 31; ++it) {
        const int g = w + it * 8;
        {   // refill aE <- tile g+8 (consumed by burstE at end of this iteration)
            const f16x8* P = Ahp + (size_t)(g + 8) * 576 + l;
            #pragma unroll
            for (int s = 0; s < 9; ++s) aE[s] = P[s * 64];
        }
        // burst odd tile g+4
        o0 = {}; o1 = {};
        #pragma unroll
        for (int s = 0; s < 9; ++s) {
            o0 = __builtin_amdgcn_mfma_f32_32x32x16_f16(aO[s], B0[s], o0, 0, 0, 0);
            o1 = __builtin_amdgcn_mfma_f32_32x32x16_f16(aO[s], B1[s], o1, 0, 0, 0);
        }
        // deferred tail: even tile g (burst issued one burst ago)
        {
            float m0 = tree16(e0), m1 = tree16(e1);
            ins6(packmin(m0, idv), gv);
            ins6(packmin(m1, idv), hv);
        }
        {   // refill aO <- tile g+12 (consumed by burstO next iteration / epilogue)
            const f16x8* P = Ahp + (size_t)(g + 12) * 576 + l;
            #pragma unroll
            for (int s = 0; s < 9; ++s) aO[s] = P[s * 64];
        }
        // burst even tile g+8
        e0 = {}; e1 = {};
        #pragma unroll
        for (int s = 0; s < 9; ++s) {
            e0 = __builtin_amdgcn_mfma_f32_32x32x16_f16(aE[s], B0[s], e0, 0, 0, 0);
            e1 = __builtin_amdgcn_mfma_f32_32x32x16_f16(aE[s], B1[s], e1, 0, 0, 0);
        }
        // deferred tail: odd tile g+4
        {
            float m0 = tree16(o0), m1 = tree16(o1);
            ins6(packmin(m0, idv + 8u), gv);
            ins6(packmin(m1, idv + 8u), hv);
        }
        idv += 16u;
    }
    // epilogue: last odd tile w+252 (aO loaded at it=30), then both remaining tails
    o0 = {}; o1 = {};
    #pragma unroll
    for (int s = 0; s < 9; ++s) {
        o0 = __builtin_amdgcn_mfma_f32_32x32x16_f16(aO[s], B0[s], o0, 0, 0, 0);
        o1 = __builtin_amdgcn_mfma_f32_32x32x16_f16(aO[s], B1[s], o1, 0, 0, 0);
    }
    {   // tail even tile w+248
        float m0 = tree16(e0), m1 = tree16(e1);
        ins6(packmin(m0, idv), gv);
        ins6(packmin(m1, idv), hv);
    }
    {   // tail odd tile w+252
        float m0 = tree16(o0), m1 = tree16(o1);
        ins6(packmin(m0, idv + 8u), gv);
        ins6(packmin(m1, idv + 8u), hv);
    }

    // ===== Phase 4: cross-wave merge per pixel, write cand (6 groups + z2) =====
    __syncthreads();
    float* Ms = Xs;   // [64 px][8 slots][6]
    const int slot = (w << 1) | half;
    #pragma unroll
    for (int q = 0; q < 6; ++q) {
        Ms[(pcol * 8 + slot) * 6 + q] = gv[q];
        Ms[((32 + pcol) * 8 + slot) * 6 + q] = hv[q];
    }
    __syncthreads();
    if (t < 64) {
        float v6[6] = {3e38f, 3e38f, 3e38f, 3e38f, 3e38f, 3e38f};
        #pragma unroll
        for (int s = 0; s < 48; ++s) ins6(Ms[t * 48 + s], v6);
        float z2 = z2p[t*4+0] + z2p[t*4+1] + z2p[t*4+2] + z2p[t*4+3];
        cand[(size_t)(n0 + t) * 2 + 0] = make_float4(v6[0], v6[1], v6[2], v6[3]);
        cand[(size_t)(n0 + t) * 2 + 1] = make_float4(v6[4], v6[5], z2, 0.f);
    }
}

// ---------------- K3: early-exit exact fp32 over candidate groups ----------------
// Two partial-sum chains (s0/s1) halve the dependent-FMA depth per code.
__global__ __launch_bounds__(256) void k_rec(
    const float* __restrict__ zws, const float* __restrict__ emb,
    const float4* __restrict__ cand, int* __restrict__ idxws,
    float* __restrict__ out_idxf, float* __restrict__ losssum,
    int* __restrict__ rlistA, int* __restrict__ rcntA,
    int* __restrict__ rlistB, int* __restrict__ rcntB)
{
    __shared__ float lred[16];
    const int t = threadIdx.x;
    const int pl = t >> 4, j = t & 15;
    const int n = blockIdx.x * 16 + pl;

    const float4 za = *(const float4*)&zws[(size_t)n * 128 + j * 8];
    const float4 zb = *(const float4*)&zws[(size_t)n * 128 + j * 8 + 4];
    const float4 c0 = cand[(size_t)n * 2 + 0];
    const float4 c1 = cand[(size_t)n * 2 + 1];
    const float pv[6] = {c0.x, c0.y, c0.z, c0.w, c1.x, c1.y};
    const float pbase = c1.z - 512.0f;   // d = packed + pbase

    float d1 = 3e38f, d2 = 3e38f; int i1 = 0x7fffffff, i2 = 0x7fffffff;
    bool safe = false;
    float lastgmin = 0.f;
    for (int q = 0; q < 6; ++q) {
        uint32_t bits = __float_as_uint(pv[q]);
        float gmin = __uint_as_float(bits & 0xFFFFFE00u);
        lastgmin = gmin;
        if (gmin >= d1 - pbase + EPS_STOP) { safe = true; break; }
        const int mbase = (int)((bits >> 1) & 255u) * 32 + (int)((bits & 1u) << 2); // tile*32 + half*4
        #pragma unroll
        for (int c = 0; c < 16; ++c) {
            int m = mbase + (c & 3) + 8 * (c >> 2);
            const float4 ea = *(const float4*)&emb[(size_t)m * 128 + j * 8];
            const float4 eb = *(const float4*)&emb[(size_t)m * 128 + j * 8 + 4];
            float da0 = za.x - ea.x, da1 = za.y - ea.y, da2 = za.z - ea.z, da3 = za.w - ea.w;
            float db0 = zb.x - eb.x, db1 = zb.y - eb.y, db2 = zb.z - eb.z, db3 = zb.w - eb.w;
            float s0 = da0*da0; s0 = fmaf(da1, da1, s0); s0 = fmaf(da2, da2, s0); s0 = fmaf(da3, da3, s0);
            float s1 = db0*db0; s1 = fmaf(db1, db1, s1); s1 = fmaf(db2, db2, s1); s1 = fmaf(db3, db3, s1);
            float s = s0 + s1;
            s += __shfl_xor(s, 1, 16);
            s += __shfl_xor(s, 2, 16);
            s += __shfl_xor(s, 4, 16);
            s += __shfl_xor(s, 8, 16);
            if (s < d1 || (s == d1 && m < i1)) { d2 = d1; i2 = i1; d1 = s; i1 = m; }
            else if (s < d2) { d2 = s; i2 = m; }
        }
    }
    if (!safe && lastgmin >= d1 - pbase + EPS_STOP) safe = true;  // post-check vs pv[5]

    if (j == 0) {
        idxws[n] = i1;
        out_idxf[n] = (float)i1;
        if (!safe) {
            int s = atomicAdd(rcntA, 1);
            if (s < RCAPA) rlistA[s] = n;
        } else if ((d2 - d1) < TAUF) {
            int s = atomicAdd(rcntB, 1);
            if (s < RCAP) { int4 v4 = make_int4(n, i1, i2, 0); ((int4*)rlistB)[s] = v4; }
        }
        lred[pl] = d1;
    }
    __syncthreads();
    if (t == 0) {
        float ls = 0.f;
        #pragma unroll
        for (int q = 0; q < 16; ++q) ls += lred[q];
        atomicAdd(losssum, ls);
    }
}

// ---------------- K4a: parallel full scan for !safe pixels ----------------
// Two fp64 partial sums halve the dependent chain per code.
__global__ __launch_bounds__(256) void k_scanp(
    const float* __restrict__ zws, const float* __restrict__ emb,
    const int* __restrict__ rcntA, const int* __restrict__ rlistA,
    double* __restrict__ scand, int* __restrict__ scani)
{
    int cnt = *rcntA; if (cnt > RCAPA) cnt = RCAPA;
    const int t = threadIdx.x;
    const int chunk = blockIdx.x & 31;
    const int gi = t >> 4, j = t & 15;
    __shared__ double sd[16];
    __shared__ int si[16];
    for (int e = blockIdx.x >> 5; e < cnt; e += 64) {
        const int n = rlistA[e];
        const float4 za = *(const float4*)&zws[(size_t)n * 128 + j * 8];
        const float4 zb = *(const float4*)&zws[(size_t)n * 128 + j * 8 + 4];
        double best = 1e300; int bi = 0x7fffffff;
        const int kbase = chunk * 256 + gi * 16;
        for (int c = 0; c < 16; ++c) {
            const int m = kbase + c;
            const float4 ea = *(const float4*)&emb[(size_t)m * 128 + j * 8];
            const float4 eb = *(const float4*)&emb[(size_t)m * 128 + j * 8 + 4];
            double sa = 0.0, sb = 0.0, d;
            d = (double)za.x - (double)ea.x; sa += d * d;
            d = (double)za.y - (double)ea.y; sa += d * d;
            d = (double)za.z - (double)ea.z; sa += d * d;
            d = (double)za.w - (double)ea.w; sa += d * d;
            d = (double)zb.x - (double)eb.x; sb += d * d;
            d = (double)zb.y - (double)eb.y; sb += d * d;
            d = (double)zb.z - (double)eb.z; sb += d * d;
            d = (double)zb.w - (double)eb.w; sb += d * d;
            double s = sa + sb;
            s += __shfl_xor(s, 1, 16);
            s += __shfl_xor(s, 2, 16);
            s += __shfl_xor(s, 4, 16);
            s += __shfl_xor(s, 8, 16);
            if (s < best) { best = s; bi = m; }   // m strictly increasing -> first-index
        }
        __syncthreads();
        if (j == 0) { sd[gi] = best; si[gi] = bi; }
        __syncthreads();
        if (t == 0) {
            double b = sd[0]; int ib = si[0];
            #pragma unroll
            for (int q = 1; q < 16; ++q)
                if (sd[q] < b || (sd[q] == b && si[q] < ib)) { b = sd[q]; ib = si[q]; }
            scand[e * 32 + chunk] = b;
            scani[e * 32 + chunk] = ib;
        }
    }
}

// ---------------- K4bc: fused finalize — blocks [0,32) merge chunk results (!safe),
// blocks [32,288) fp64 pair arbitration (near-tie). Pixel sets disjoint by construction.
// pairB: 4-way ILP fp64 dot + fused dual reduction (7 syncs, was 14).
__global__ __launch_bounds__(128) void k_fix(
    const float* __restrict__ x, const float* __restrict__ Wl, const float* __restrict__ bl,
    const float* __restrict__ emb,
    const int* __restrict__ rcntA, const int* __restrict__ rlistA,
    const double* __restrict__ scand, const int* __restrict__ scani,
    const int* __restrict__ rcntB, const int* __restrict__ rlistB,
    int* __restrict__ idxws, float* __restrict__ out_idxf)
{
    const int t = threadIdx.x;
    if (blockIdx.x < 32) {
        // ---- mergeA: 32 blocks, first wave only ----
        if (t < 64) {
            int cnt = *rcntA; if (cnt > RCAPA) cnt = RCAPA;
            for (int e = blockIdx.x; e < cnt; e += 32) {
                double b = 1e300; int ib = 0x7fffffff;
                if (t < 32) { b = scand[e * 32 + t]; ib = scani[e * 32 + t]; }
                #pragma unroll
                for (int o = 16; o; o >>= 1) {
                    double ob = __shfl_down(b, o, 64);
                    int oi = __shfl_down(ib, o, 64);
                    if (ob < b || (ob == b && oi < ib)) { b = ob; ib = oi; }
                }
                if (t == 0) { int n = rlistA[e]; idxws[n] = ib; out_idxf[n] = (float)ib; }
            }
        }
        return;
    }
    // ---- pairB: 256 blocks ----
    __shared__ double xs[128];
    __shared__ double red[128];
    __shared__ double red2[128];
    int cnt = *rcntB; if (cnt > RCAP) cnt = RCAP;
    for (int e = (int)blockIdx.x - 32; e < cnt; e += 256) {
        const int4 v = ((const int4*)rlistB)[e];
        const int n = v.x, c1 = v.y, c2 = v.z;
        const int b = n >> 10, hw = n & 1023;
        __syncthreads();
        xs[t] = (double)x[(size_t)(b * 128 + t) * 1024 + hw];
        __syncthreads();
        double z0 = (double)bl[t], z1 = 0.0, z2 = 0.0, z3 = 0.0;
        const float* wr = &Wl[(size_t)t * 128];
        #pragma unroll 8
        for (int c = 0; c < 128; c += 4) {
            z0 = fma((double)wr[c + 0], xs[c + 0], z0);
            z1 = fma((double)wr[c + 1], xs[c + 1], z1);
            z2 = fma((double)wr[c + 2], xs[c + 2], z2);
            z3 = fma((double)wr[c + 3], xs[c + 3], z3);
        }
        double z = (z0 + z1) + (z2 + z3);
        double da = z - (double)emb[(size_t)c1 * 128 + t];
        double db = z - (double)emb[(size_t)c2 * 128 + t];
        red[t] = da * da; red2[t] = db * db;
        __syncthreads();
        for (int o = 64; o; o >>= 1) {
            if (t < o) { red[t] += red[t + o]; red2[t] += red2[t + o]; }
            __syncthreads();
        }
        if (t == 0) {
            double d1v = red[0], d2v = red2[0];
            int win = (d2v < d1v || (d2v == d1v && c2 < c1)) ? c2 : c1;
            idxws[n] = win;
            out_idxf[n] = (float)win;
        }
        __syncthreads();
    }
}

// ---------------- K5: gather + transpose + histogram ----------------
// 512 blocks x 256 thr: each block = 64 pixels; each wave owns one channel-quarter.
__global__ __launch_bounds__(256) void k_out(
    const float* __restrict__ emb, const int* __restrict__ idxws,
    float* __restrict__ outp /* d_out + 1 */, float* __restrict__ counts)
{
    const int t = threadIdx.x;
    const int b  = blockIdx.x >> 4;          // 32 batches
    const int h2 = blockIdx.x & 15;          // 16 groups of 64 pixels
    const int pix = t & 63;
    const int cq  = t >> 6;                  // channel quarter (one per wave)
    const int n = b * 1024 + h2 * 64 + pix;
    const int id = idxws[n];
    if (cq == 0) atomicAdd(&counts[id], 1.0f);
    const float4* ep = (const float4*)&emb[(size_t)id * 128 + cq * 32];
    float* ob = outp + (size_t)b * 131072 + (size_t)cq * 32768 + h2 * 64 + pix;
    #pragma unroll
    for (int c4 = 0; c4 < 8; ++c4) {
        float4 v = ep[c4];
        __builtin_nontemporal_store(v.x, &ob[(c4 * 4 + 0) * 1024]);
        __builtin_nontemporal_store(v.y, &ob[(c4 * 4 + 1) * 1024]);
        __builtin_nontemporal_store(v.z, &ob[(c4 * 4 + 2) * 1024]);
        __builtin_nontemporal_store(v.w, &ob[(c4 * 4 + 3) * 1024]);
    }
}

// ---------------- K6: finalize loss + perplexity ----------------
__global__ __launch_bounds__(256) void k_final(
    const float* __restrict__ counts, const float* __restrict__ losssum, float* __restrict__ d_out)
{
    const int t = threadIdx.x;
    float ent = 0.f;
    for (int k = t; k < KCB; k += 256) {
        float p = counts[k] * (1.0f / 32768.0f);
        ent -= p * logf(p + 1e-10f);
    }
    #pragma unroll
    for (int o = 32; o; o >>= 1) ent += __shfl_down(ent, o, 64);
    __shared__ float wred[4];
    if ((t & 63) == 0) wred[t >> 6] = ent;
    __syncthreads();
    if (t == 0) {
        float e = wred[0] + wred[1] + wred[2] + wred[3];
        d_out[0] = 1.25f * (*losssum) * (1.0f / 4194304.0f);
        d_out[OUT_OFF_PERP] = expf(e);
    }
}

extern "C" void kernel_launch(void* const* d_in, const int* in_sizes, int n_in,
                              void* d_out, int out_size, void* d_ws, size_t ws_size,
                              hipStream_t stream) {
    (void)in_sizes; (void)n_in; (void)out_size; (void)ws_size;
    const float* x   = (const float*)d_in[0];
    const float* Wl  = (const float*)d_in[1];
    const float* bl  = (const float*)d_in[2];
    const float* emb = (const float*)d_in[3];
    float* out = (float*)d_out;
    char*  ws  = (char*)d_ws;

    _Float16* embFh = (_Float16*)(ws + WS_EMBFH);
    float* zws     = (float*)(ws + WS_ZWS);
    float4* cand   = (float4*)(ws + WS_CAND);
    int*   idxws   = (int*)  (ws + WS_IDX);
    int*   rlistA  = (int*)  (ws + WS_RLISTA);
    int*   rlistB  = (int*)  (ws + WS_RLISTB);
    double* scand  = (double*)(ws + WS_SCAND);
    int*   scani   = (int*)  (ws + WS_SCANI);
    float* counts  = (float*)(ws + WS_COUNTS);
    float* losssum = (float*)(ws + WS_LOSS);
    int*   rcntA   = (int*)  (ws + WS_RCNTA);
    int*   rcntB   = (int*)  (ws + WS_RCNTB);
    int*   zerobuf = (int*)  (ws + WS_ZERO_OFF);

    k_prep2<<<KCB / 4, 256, 0, stream>>>(emb, embFh, zerobuf);
    k_main<<<NPIX / 64, 256, 0, stream>>>(x, Wl, bl, embFh, zws, cand);
    k_rec<<<NPIX / 16, 256, 0, stream>>>(zws, emb, cand, idxws, out + OUT_OFF_IDX,
                                         losssum, rlistA, rcntA, rlistB, rcntB);
    k_scanp<<<2048, 256, 0, stream>>>(zws, emb, rcntA, rlistA, scand, scani);
    k_fix<<<288, 128, 0, stream>>>(x, Wl, bl, emb, rcntA, rlistA, scand, scani,
                                   rcntB, rlistB, idxws, out + OUT_OFF_IDX);
    k_out<<<512, 256, 0, stream>>>(emb, idxws, out + OUT_OFF_OUT, counts);
    k_final<<<1, 256, 0, stream>>>(counts, losssum, out);
}